// Round 6
// baseline (206.184 us; speedup 1.0000x reference)
//
#include <hip/hip_runtime.h>

#define S_ 2304   // 48*48

typedef unsigned short u16;
typedef __attribute__((ext_vector_type(8))) short bf16x8;
typedef __attribute__((ext_vector_type(4))) float f32x4;

static __device__ __forceinline__ u16 f2bf(float x) {
  union { float f; unsigned u; } v; v.f = x;
  unsigned r = v.u + 0x7FFFu + ((v.u >> 16) & 1u);
  return (u16)(r >> 16);
}
static __device__ __forceinline__ float bf2f(u16 h) {
  union { unsigned u; float f; } v; v.u = ((unsigned)h) << 16; return v.f;
}

// ---------------------------------------------------------------------------
// Weight split: fp32 -> bf16 hi + bf16 lo(residual). n multiple of 1024.
// ---------------------------------------------------------------------------
__global__ __launch_bounds__(256) void splitw_kernel(
    const float* __restrict__ w, u16* __restrict__ wh, u16* __restrict__ wl)
{
  int id = blockIdx.x * 256 + threadIdx.x;
  float4 v = ((const float4*)w)[id];
  short4 h, l;
  float f[4] = {v.x, v.y, v.z, v.w};
  u16 hh[4], ll[4];
#pragma unroll
  for (int q = 0; q < 4; q++) {
    hh[q] = f2bf(f[q]);
    ll[q] = f2bf(f[q] - bf2f(hh[q]));
  }
  h.x = hh[0]; h.y = hh[1]; h.z = hh[2]; h.w = hh[3];
  l.x = ll[0]; l.y = ll[1]; l.z = ll[2]; l.w = ll[3];
  ((short4*)wh)[id] = h;
  ((short4*)wl)[id] = l;
}

// ---------------------------------------------------------------------------
// Split-transpose: in[b][256][2304] fp32 -> outh/outl[b][2304][256] bf16 h/l.
// 64x64 tiles via LDS (u32-packed h|l). Grid (36, 4, 4b).
// ---------------------------------------------------------------------------
__global__ __launch_bounds__(256) void split_transpose_kernel(
    const float* __restrict__ in, u16* __restrict__ outh, u16* __restrict__ outl)
{
  __shared__ unsigned tile[64][65];
  const int s0 = blockIdx.x * 64, c0 = blockIdx.y * 64, b = blockIdx.z;
  const float* inb = in + (size_t)b * 256 * S_;
  u16* oh = outh + (size_t)b * S_ * 256;
  u16* ol = outl + (size_t)b * S_ * 256;
  const int tid = threadIdx.x;
#pragma unroll
  for (int it = 0; it < 4; it++) {
    int id = tid + it * 256;
    int c = id >> 4, s4 = (id & 15) * 4;
    float4 v = *(const float4*)&inb[(size_t)(c0 + c) * S_ + s0 + s4];
    float f[4] = {v.x, v.y, v.z, v.w};
#pragma unroll
    for (int q = 0; q < 4; q++) {
      u16 h = f2bf(f[q]);
      u16 l = f2bf(f[q] - bf2f(h));
      tile[s4 + q][c] = (unsigned)h | ((unsigned)l << 16);
    }
  }
  __syncthreads();
#pragma unroll
  for (int it = 0; it < 4; it++) {
    int id = tid + it * 256;
    int s = id >> 4, c4 = (id & 15) * 4;
    short4 h, l;
    unsigned p0 = tile[s][c4 + 0], p1 = tile[s][c4 + 1];
    unsigned p2 = tile[s][c4 + 2], p3 = tile[s][c4 + 3];
    h.x = (short)(p0 & 0xffff); h.y = (short)(p1 & 0xffff);
    h.z = (short)(p2 & 0xffff); h.w = (short)(p3 & 0xffff);
    l.x = (short)(p0 >> 16); l.y = (short)(p1 >> 16);
    l.z = (short)(p2 >> 16); l.w = (short)(p3 >> 16);
    *(short4*)&oh[(size_t)(s0 + s) * 256 + c0 + c4] = h;
    *(short4*)&ol[(size_t)(s0 + s) * 256 + c0 + c4] = l;
  }
}

// ---------------------------------------------------------------------------
// MFMA split-bf16 GEMM with B-prefetch pipeline.
// Out[b][m][s] = sum_k W[m][k] X[b][k][s] + bias[m]; 3-pass split.
// BM=64, BN=128, K=256 (8 ksteps of 32). 256 thr = 4 waves, wave tile 64x32.
// W-tiles dbuf in LDS; B-frags prefetched global->reg one kstep ahead.
// ---------------------------------------------------------------------------
__global__ __launch_bounds__(256) void gemm_mfma_kernel(
    const u16* __restrict__ Wh, const u16* __restrict__ Wl,
    const float* __restrict__ bias,
    const u16* __restrict__ XTh, const u16* __restrict__ XTl,
    float* __restrict__ Out, int M)
{
  __shared__ u16 wAh[2][64 * 40];   // 5120 B per buf
  __shared__ u16 wAl[2][64 * 40];
  const int MB = M >> 6;
  const int xcd = blockIdx.x & 7;
  const int idx = blockIdx.x >> 3;          // 0 .. 9*MB-1
  const int g = xcd * 9 + idx / MB;         // 0..71 group = (n_blk, b)
  const int mb = idx % MB;
  const int nb = g % 18, b = g / 18;
  const int m0 = mb * 64, n0 = nb * 128;
  const int tid = threadIdx.x;
  const int wv = tid >> 6, lane = tid & 63;
  const int lr = lane & 15, lg = lane >> 4;
  const bf16x8 zv = {0, 0, 0, 0, 0, 0, 0, 0};

  const u16* xbh = XTh + ((size_t)b * S_ + n0 + wv * 32) * 256;
  const u16* xbl = XTl + ((size_t)b * S_ + n0 + wv * 32) * 256;

  f32x4 acc[4][2];
#pragma unroll
  for (int mt = 0; mt < 4; mt++)
#pragma unroll
    for (int nt = 0; nt < 2; nt++) acc[mt][nt] = (f32x4){0.f, 0.f, 0.f, 0.f};

#define STAGE_W(t, buf)                                                      \
  {                                                                          \
    _Pragma("unroll")                                                        \
    for (int r = 0; r < 2; r++) {                                            \
      int id = tid + r * 256;                                                \
      int m = id >> 3, k4 = (id & 7) * 4;                                    \
      *(short4*)&wAh[buf][m * 40 + k4] =                                     \
          *(const short4*)&Wh[(size_t)(m0 + m) * 256 + (t) * 32 + k4];       \
      *(short4*)&wAl[buf][m * 40 + k4] =                                     \
          *(const short4*)&Wl[(size_t)(m0 + m) * 256 + (t) * 32 + k4];       \
    }                                                                        \
  }

  STAGE_W(0, 0);
  // B prologue: kstep 0
  bf16x8 cbh[2], cbl[2];
#pragma unroll
  for (int nt = 0; nt < 2; nt++) {
    size_t off = (size_t)(nt * 16 + lr) * 256 + lg * 8;
    cbh[nt] = *(const bf16x8*)&xbh[off];
    cbl[nt] = *(const bf16x8*)&xbl[off];
  }
  __syncthreads();

  for (int t = 0; t < 8; t++) {
    int buf = t & 1;
    if (t < 7) STAGE_W(t + 1, buf ^ 1);

    // prefetch next-kstep B fragments (global, independent of LDS bufs)
    bf16x8 nbh[2], nbl[2];
    if (t < 7) {
#pragma unroll
      for (int nt = 0; nt < 2; nt++) {
        size_t off = (size_t)(nt * 16 + lr) * 256 + (t + 1) * 32 + lg * 8;
        nbh[nt] = *(const bf16x8*)&xbh[off];
        nbl[nt] = *(const bf16x8*)&xbl[off];
      }
    } else {
#pragma unroll
      for (int nt = 0; nt < 2; nt++) { nbh[nt] = zv; nbl[nt] = zv; }
    }

    // A fragments from LDS
    bf16x8 ah[4], al[4];
#pragma unroll
    for (int mt = 0; mt < 4; mt++) {
      ah[mt] = *(const bf16x8*)&wAh[buf][(mt * 16 + lr) * 40 + lg * 8];
      al[mt] = *(const bf16x8*)&wAl[buf][(mt * 16 + lr) * 40 + lg * 8];
    }
#pragma unroll
    for (int mt = 0; mt < 4; mt++)
#pragma unroll
      for (int nt = 0; nt < 2; nt++) {
        acc[mt][nt] = __builtin_amdgcn_mfma_f32_16x16x32_bf16(ah[mt], cbh[nt], acc[mt][nt], 0, 0, 0);
        acc[mt][nt] = __builtin_amdgcn_mfma_f32_16x16x32_bf16(ah[mt], cbl[nt], acc[mt][nt], 0, 0, 0);
        acc[mt][nt] = __builtin_amdgcn_mfma_f32_16x16x32_bf16(al[mt], cbh[nt], acc[mt][nt], 0, 0, 0);
      }
    __syncthreads();
#pragma unroll
    for (int nt = 0; nt < 2; nt++) { cbh[nt] = nbh[nt]; cbl[nt] = nbl[nt]; }
  }

  // epilogue: D col = lane&15 (s), row = lg*4+reg (m)
  float* ob = Out + (size_t)b * M * S_;
#pragma unroll
  for (int mt = 0; mt < 4; mt++) {
    float4 b4 = *(const float4*)&bias[m0 + mt * 16 + lg * 4];
    float bv[4] = {b4.x, b4.y, b4.z, b4.w};
#pragma unroll
    for (int nt = 0; nt < 2; nt++) {
      int s = n0 + wv * 32 + nt * 16 + lr;
#pragma unroll
      for (int r = 0; r < 4; r++) {
        int m = m0 + mt * 16 + lg * 4 + r;
        ob[(size_t)m * S_ + s] = acc[mt][nt][r] + bv[r];
      }
    }
  }
#undef STAGE_W
}

// ---------------------------------------------------------------------------
// Row attention: per (b,n,h): S[i,w] = SCALE*sum_d rq[d,i,w]*rk[d,h,w],
// softmax over i (columns), store transposed bf16: arT[b,n,h][w][i].
// ---------------------------------------------------------------------------
__global__ __launch_bounds__(256) void row_attn_kernel(
    const float* __restrict__ rcv, u16* __restrict__ arT)
{
  __shared__ u16  rq[16 * 2304];     // [d][i*48+w]  73728 B
  __shared__ float rk[16 * 48];
  __shared__ float Sm[48 * 49];      // [i][w] padded
  __shared__ float cmax[48], crs[48];
  const int hg = blockIdx.x, n = blockIdx.y, b = blockIdx.z;
  const float* base = rcv + ((size_t)b * 768 + n * 96) * S_;  // rq; rk at +16*S_
  const int tid = threadIdx.x;

  for (int id = tid; id < 9216; id += 256) {     // 16*2304/4 float4s
    float4 v = *(const float4*)&base[id * 4];
    short4 s;
    s.x = (short)f2bf(v.x); s.y = (short)f2bf(v.y);
    s.z = (short)f2bf(v.z); s.w = (short)f2bf(v.w);
    *(short4*)&rq[id * 4] = s;
  }

  for (int hh = 0; hh < 6; hh++) {
    int h = hg * 6 + hh;
    for (int id = tid; id < 768; id += 256) {
      int d = id / 48, w = id % 48;
      rk[id] = base[(size_t)(16 + d) * S_ + h * 48 + w];
    }
    __syncthreads();
    for (int id = tid; id < 2304; id += 256) {
      int i = id / 48, w = id % 48;
      float s = 0.f;
#pragma unroll
      for (int d = 0; d < 16; d++)
        s += bf2f(rq[d * 2304 + i * 48 + w]) * rk[d * 48 + w];
      Sm[i * 49 + w] = s * 0.25f;
    }
    __syncthreads();
    if (tid < 48) {
      int w = tid;
      float m = -1e30f;
      for (int i = 0; i < 48; i++) m = fmaxf(m, Sm[i * 49 + w]);
      float s = 0.f;
      for (int i = 0; i < 48; i++) s += __expf(Sm[i * 49 + w] - m);
      cmax[w] = m; crs[w] = 1.0f / s;
    }
    __syncthreads();
    u16* dst = arT + ((size_t)(b * 8 + n) * 48 + h) * 2304;
    for (int id = tid; id < 2304; id += 256) {
      int w = id / 48, i = id % 48;
      float p = __expf(Sm[i * 49 + w] - cmax[w]) * crs[w];
      dst[id] = f2bf(p);                  // layout [w][i]
    }
    __syncthreads();
  }
}

// ---------------------------------------------------------------------------
// Col attention: per (b,n,h): T[w,j] = SCALE*sum_d ck[d,h,w]*cq[d,h,j],
// softmax over j (rows), store bf16: awT[b,n,h][w][j].
// ---------------------------------------------------------------------------
__global__ __launch_bounds__(256) void col_attn_kernel(
    const float* __restrict__ rcv, u16* __restrict__ awT)
{
  __shared__ float cq[16 * 48], ck[16 * 48];
  __shared__ float Tm[48 * 49];
  __shared__ float rmax[48], rrs[48];
  const int hg = blockIdx.x, n = blockIdx.y, b = blockIdx.z;
  const float* base = rcv + ((size_t)b * 768 + n * 96 + 32) * S_; // cq; ck at +16*S_
  const int tid = threadIdx.x;

  for (int hh = 0; hh < 6; hh++) {
    int h = hg * 6 + hh;
    for (int id = tid; id < 768; id += 256) {
      int d = id / 48, j = id % 48;
      cq[id] = base[(size_t)d * S_ + h * 48 + j];
      ck[id] = base[(size_t)(16 + d) * S_ + h * 48 + j];
    }
    __syncthreads();
    for (int id = tid; id < 2304; id += 256) {
      int w = id / 48, j = id % 48;
      float t = 0.f;
#pragma unroll
      for (int d = 0; d < 16; d++)
        t += ck[d * 48 + w] * cq[d * 48 + j];
      Tm[w * 49 + j] = t * 0.25f;
    }
    __syncthreads();
    if (tid < 48) {
      int w = tid;
      float m = -1e30f;
      for (int j = 0; j < 48; j++) m = fmaxf(m, Tm[w * 49 + j]);
      float s = 0.f;
      for (int j = 0; j < 48; j++) s += __expf(Tm[w * 49 + j] - m);
      rmax[w] = m; rrs[w] = 1.0f / s;
    }
    __syncthreads();
    u16* dst = awT + ((size_t)(b * 8 + n) * 48 + h) * 2304;
    for (int id = tid; id < 2304; id += 256) {
      int w = id / 48, j = id % 48;
      float p = __expf(Tm[w * 49 + j] - rmax[w]) * rrs[w];
      dst[id] = f2bf(p);                  // layout [w][j]
    }
    __syncthreads();
  }
}

// ---------------------------------------------------------------------------
// Main contraction + PE conv, wave-independent + software-pipelined:
// aw B-fragments prefetched one h ahead (global->reg); ar loads issued at
// top of body so they're in flight during the MFMA block; setprio around
// MFMA cluster. __launch_bounds__(256,4) caps VGPR at 128 (4 blocks/CU).
// ---------------------------------------------------------------------------
__global__ __launch_bounds__(256, 4) void attn_main_kernel(
    const float* __restrict__ rcv, const u16* __restrict__ arT,
    const u16* __restrict__ awT, const float* __restrict__ pe_w,
    const float* __restrict__ pe_b, float* __restrict__ y)
{
  __shared__ u16 vA[192 * 72];        // 27648 B  [(dloc,i)][j pad]
  const int id0 = blockIdx.x;
  const int n = id0 & 7;              // XCD swizzle
  const int rest = id0 >> 3;          // 0..127
  const int b = rest >> 5;            // 0..3
  const int inner = rest & 31;        // 0..31
  const int dchunk = inner >> 2;      // 0..7
  const int hc = inner & 3;           // 0..3
  const int h0 = hc * 12;
  const int tid = threadIdx.x;
  const int wave = tid >> 6, lane = tid & 63;
  const int lr = lane & 15, lg = lane >> 4;

  for (int id = tid; id < 192 * 24; id += 256) {
    int row = id / 24, col = 48 + id % 24;
    vA[row * 72 + col] = 0;
  }
  const float* vbase = rcv + ((size_t)b * 768 + n * 96 + 64 + dchunk * 4) * S_;
  for (int id = tid; id < 2304; id += 256) {   // 4 planes * 576 float4
    int dl = id / 576, rem = id % 576;
    int i = rem / 12, j4 = (rem % 12) * 4;
    float4 v = *(const float4*)&vbase[(size_t)dl * S_ + i * 48 + j4];
    short4 s;
    s.x = (short)f2bf(v.x); s.y = (short)f2bf(v.y);
    s.z = (short)f2bf(v.z); s.w = (short)f2bf(v.w);
    *(short4*)&vA[(dl * 48 + i) * 72 + j4] = s;
  }
  __syncthreads();   // the only barrier

  const size_t bnh0 = ((size_t)(b * 8 + n) * 48) * 2304;
  const int c = n * 32 + dchunk * 4 + wave;
  float pw[9];
#pragma unroll
  for (int t = 0; t < 9; t++) pw[t] = pe_w[c * 9 + t];
  const float pb = pe_b[c];
  float* yg = y + ((size_t)b * 256 + c) * S_;
  const int vrow0 = wave * 48;
  const bf16x8 zv = {0, 0, 0, 0, 0, 0, 0, 0};

  // prologue: aw fragments for h0
  bf16x8 cb0[3], cb1[3];
  {
    const u16* aw0 = awT + bnh0 + (size_t)h0 * 2304;
#pragma unroll
    for (int nt = 0; nt < 3; nt++) {
      int row = (nt * 16 + lr) * 48;
      cb0[nt] = *(const bf16x8*)&aw0[row + lg * 8];
      cb1[nt] = (lg < 2) ? *(const bf16x8*)&aw0[row + 32 + lg * 8] : zv;
    }
  }

  for (int hh = 0; hh < 12; hh++) {
    const int h = h0 + hh;
    const u16* arg = arT + bnh0 + (size_t)h * 2304;  // [w][i]

    // issue all ar loads now (consumed after the MFMA block)
    short4 sar[3][3];
#pragma unroll
    for (int nt = 0; nt < 3; nt++)
#pragma unroll
      for (int mt = 0; mt < 3; mt++)
        sar[nt][mt] = *(const short4*)&arg[(nt * 16 + lr) * 48 + mt * 16 + lg * 4];

    // prefetch next-h aw fragments (consumed next iteration)
    bf16x8 nb0[3], nb1[3];
    if (hh < 11) {
      const u16* awn = awT + bnh0 + (size_t)(h + 1) * 2304;
#pragma unroll
      for (int nt = 0; nt < 3; nt++) {
        int row = (nt * 16 + lr) * 48;
        nb0[nt] = *(const bf16x8*)&awn[row + lg * 8];
        nb1[nt] = (lg < 2) ? *(const bf16x8*)&awn[row + 32 + lg * 8] : zv;
      }
    } else {
#pragma unroll
      for (int nt = 0; nt < 3; nt++) { nb0[nt] = zv; nb1[nt] = zv; }
    }

    f32x4 acc[3][3];
#pragma unroll
    for (int mt = 0; mt < 3; mt++)
#pragma unroll
      for (int nt = 0; nt < 3; nt++) acc[mt][nt] = (f32x4){0.f, 0.f, 0.f, 0.f};

    __builtin_amdgcn_s_setprio(1);
#pragma unroll
    for (int mt = 0; mt < 3; mt++) {
      bf16x8 a0 = *(const bf16x8*)&vA[(vrow0 + mt * 16 + lr) * 72 + lg * 8];
      bf16x8 a1 = *(const bf16x8*)&vA[(vrow0 + mt * 16 + lr) * 72 + 32 + lg * 8];
#pragma unroll
      for (int nt = 0; nt < 3; nt++) {
        acc[mt][nt] = __builtin_amdgcn_mfma_f32_16x16x32_bf16(a0, cb0[nt], acc[mt][nt], 0, 0, 0);
        acc[mt][nt] = __builtin_amdgcn_mfma_f32_16x16x32_bf16(a1, cb1[nt], acc[mt][nt], 0, 0, 0);
      }
    }
    __builtin_amdgcn_s_setprio(0);

    float pv[3];
#pragma unroll
    for (int nt = 0; nt < 3; nt++) {
      float p = 0.f;
#pragma unroll
      for (int mt = 0; mt < 3; mt++) {
        short4 s = sar[nt][mt];
        p += bf2f((u16)s.x) * acc[mt][nt][0] + bf2f((u16)s.y) * acc[mt][nt][1]
           + bf2f((u16)s.z) * acc[mt][nt][2] + bf2f((u16)s.w) * acc[mt][nt][3];
      }
      p += __shfl_xor(p, 16);
      p += __shfl_xor(p, 32);
      pv[nt] = p;
    }

    if (lane < 48) {
      float a = (lane < 16) ? pv[0] : (lane < 32 ? pv[1] : pv[2]);
      a += pb;
      int ww = lane;
#pragma unroll
      for (int kh = -1; kh <= 1; kh++) {
        int ih = h + kh;
        if (ih < 0 || ih > 47) continue;
#pragma unroll
        for (int kw = -1; kw <= 1; kw++) {
          int jw = ww + kw;
          if (jw < 0 || jw > 47) continue;
          a += pw[(kh + 1) * 3 + (kw + 1)] * bf2f(vA[(vrow0 + ih) * 72 + jw]);
        }
      }
      yg[h * 48 + ww] = a;
    }

    // rotate prefetched aw fragments
#pragma unroll
    for (int nt = 0; nt < 3; nt++) { cb0[nt] = nb0[nt]; cb1[nt] = nb1[nt]; }
  }
}

// ---------------------------------------------------------------------------
extern "C" void kernel_launch(void* const* d_in, const int* in_sizes, int n_in,
                              void* d_out, int out_size, void* d_ws, size_t ws_size,
                              hipStream_t stream) {
  const float* x      = (const float*)d_in[0];
  const float* rcv_w  = (const float*)d_in[1];
  const float* rcv_b  = (const float*)d_in[2];
  const float* pe_w   = (const float*)d_in[3];
  const float* pe_b   = (const float*)d_in[4];
  const float* proj_w = (const float*)d_in[5];
  const float* proj_b = (const float*)d_in[6];
  float* out = (float*)d_out;

  char* ws = (char*)d_ws;
  float* rcv = (float*)ws;                         // 28,311,552 B
  u16*   arT = (u16*)(ws + 28311552);              //  7,077,888 B
  u16*   awT = (u16*)(ws + 35389440);              //  7,077,888 B
  float* y   = (float*)(ws + 42467328);            //  9,437,184 B
  u16*   xTh = (u16*)(ws + 51904512);              //  4,718,592 B
  u16*   xTl = (u16*)(ws + 56623104);              //  4,718,592 B
  u16*   Whr = (u16*)(ws + 61341696);              //    393,216 B
  u16*   Wlr = (u16*)(ws + 61734912);              //    393,216 B
  u16*   Whp = (u16*)(ws + 62128128);              //    131,072 B
  u16*   Wlp = (u16*)(ws + 62259200);              //    131,072 B
  // yT aliases arT/awT region (free after attn_main)
  u16*   yTh = arT;
  u16*   yTl = awT;

  splitw_kernel<<<dim3(192), 256, 0, stream>>>(rcv_w, Whr, Wlr);
  splitw_kernel<<<dim3(64),  256, 0, stream>>>(proj_w, Whp, Wlp);
  split_transpose_kernel<<<dim3(36, 4, 4), 256, 0, stream>>>(x, xTh, xTl);
  gemm_mfma_kernel<<<dim3(72 * 12), 256, 0, stream>>>(Whr, Wlr, rcv_b, xTh, xTl, rcv, 768);
  row_attn_kernel<<<dim3(8, 8, 4), 256, 0, stream>>>(rcv, arT);
  col_attn_kernel<<<dim3(8, 8, 4), 256, 0, stream>>>(rcv, awT);
  attn_main_kernel<<<dim3(1024), 256, 0, stream>>>(rcv, arT, awT, pe_w, pe_b, y);
  split_transpose_kernel<<<dim3(36, 4, 4), 256, 0, stream>>>(y, yTh, yTl);
  gemm_mfma_kernel<<<dim3(72 * 4), 256, 0, stream>>>(Whp, Wlp, proj_b, yTh, yTl, out, 256);
}

// Round 7
// 181.012 us; speedup vs baseline: 1.1391x; 1.1391x over previous
//
#include <hip/hip_runtime.h>

#define S_ 2304   // 48*48

typedef unsigned short u16;
typedef __attribute__((ext_vector_type(8))) short bf16x8;
typedef __attribute__((ext_vector_type(4))) float f32x4;

static __device__ __forceinline__ u16 f2bf(float x) {
  union { float f; unsigned u; } v; v.f = x;
  unsigned r = v.u + 0x7FFFu + ((v.u >> 16) & 1u);
  return (u16)(r >> 16);
}
static __device__ __forceinline__ float bf2f(u16 h) {
  union { unsigned u; float f; } v; v.u = ((unsigned)h) << 16; return v.f;
}

// ---------------------------------------------------------------------------
// Weight split: fp32 -> bf16 hi + bf16 lo(residual). n multiple of 1024.
// ---------------------------------------------------------------------------
__global__ __launch_bounds__(256) void splitw_kernel(
    const float* __restrict__ w, u16* __restrict__ wh, u16* __restrict__ wl)
{
  int id = blockIdx.x * 256 + threadIdx.x;
  float4 v = ((const float4*)w)[id];
  short4 h, l;
  float f[4] = {v.x, v.y, v.z, v.w};
  u16 hh[4], ll[4];
#pragma unroll
  for (int q = 0; q < 4; q++) {
    hh[q] = f2bf(f[q]);
    ll[q] = f2bf(f[q] - bf2f(hh[q]));
  }
  h.x = hh[0]; h.y = hh[1]; h.z = hh[2]; h.w = hh[3];
  l.x = ll[0]; l.y = ll[1]; l.z = ll[2]; l.w = ll[3];
  ((short4*)wh)[id] = h;
  ((short4*)wl)[id] = l;
}

// ---------------------------------------------------------------------------
// Split-transpose: in[b][256][2304] fp32 -> outh/outl[b][2304][256] bf16 h/l.
// 64x64 tiles via LDS (u32-packed h|l). Grid (36, 4, 4b).
// ---------------------------------------------------------------------------
__global__ __launch_bounds__(256) void split_transpose_kernel(
    const float* __restrict__ in, u16* __restrict__ outh, u16* __restrict__ outl)
{
  __shared__ unsigned tile[64][65];
  const int s0 = blockIdx.x * 64, c0 = blockIdx.y * 64, b = blockIdx.z;
  const float* inb = in + (size_t)b * 256 * S_;
  u16* oh = outh + (size_t)b * S_ * 256;
  u16* ol = outl + (size_t)b * S_ * 256;
  const int tid = threadIdx.x;
#pragma unroll
  for (int it = 0; it < 4; it++) {
    int id = tid + it * 256;
    int c = id >> 4, s4 = (id & 15) * 4;
    float4 v = *(const float4*)&inb[(size_t)(c0 + c) * S_ + s0 + s4];
    float f[4] = {v.x, v.y, v.z, v.w};
#pragma unroll
    for (int q = 0; q < 4; q++) {
      u16 h = f2bf(f[q]);
      u16 l = f2bf(f[q] - bf2f(h));
      tile[s4 + q][c] = (unsigned)h | ((unsigned)l << 16);
    }
  }
  __syncthreads();
#pragma unroll
  for (int it = 0; it < 4; it++) {
    int id = tid + it * 256;
    int s = id >> 4, c4 = (id & 15) * 4;
    short4 h, l;
    unsigned p0 = tile[s][c4 + 0], p1 = tile[s][c4 + 1];
    unsigned p2 = tile[s][c4 + 2], p3 = tile[s][c4 + 3];
    h.x = (short)(p0 & 0xffff); h.y = (short)(p1 & 0xffff);
    h.z = (short)(p2 & 0xffff); h.w = (short)(p3 & 0xffff);
    l.x = (short)(p0 >> 16); l.y = (short)(p1 >> 16);
    l.z = (short)(p2 >> 16); l.w = (short)(p3 >> 16);
    *(short4*)&oh[(size_t)(s0 + s) * 256 + c0 + c4] = h;
    *(short4*)&ol[(size_t)(s0 + s) * 256 + c0 + c4] = l;
  }
}

// ---------------------------------------------------------------------------
// MFMA split-bf16 GEMM with B-prefetch pipeline.
// Out[b][m][s] = sum_k W[m][k] X[b][k][s] + bias[m]; 3-pass split.
// BM=64, BN=128, K=256 (8 ksteps of 32). 256 thr = 4 waves, wave tile 64x32.
// W-tiles dbuf in LDS; B-frags prefetched global->reg one kstep ahead.
// ---------------------------------------------------------------------------
__global__ __launch_bounds__(256) void gemm_mfma_kernel(
    const u16* __restrict__ Wh, const u16* __restrict__ Wl,
    const float* __restrict__ bias,
    const u16* __restrict__ XTh, const u16* __restrict__ XTl,
    float* __restrict__ Out, int M)
{
  __shared__ u16 wAh[2][64 * 40];   // 5120 B per buf
  __shared__ u16 wAl[2][64 * 40];
  const int MB = M >> 6;
  const int xcd = blockIdx.x & 7;
  const int idx = blockIdx.x >> 3;          // 0 .. 9*MB-1
  const int g = xcd * 9 + idx / MB;         // 0..71 group = (n_blk, b)
  const int mb = idx % MB;
  const int nb = g % 18, b = g / 18;
  const int m0 = mb * 64, n0 = nb * 128;
  const int tid = threadIdx.x;
  const int wv = tid >> 6, lane = tid & 63;
  const int lr = lane & 15, lg = lane >> 4;
  const bf16x8 zv = {0, 0, 0, 0, 0, 0, 0, 0};

  const u16* xbh = XTh + ((size_t)b * S_ + n0 + wv * 32) * 256;
  const u16* xbl = XTl + ((size_t)b * S_ + n0 + wv * 32) * 256;

  f32x4 acc[4][2];
#pragma unroll
  for (int mt = 0; mt < 4; mt++)
#pragma unroll
    for (int nt = 0; nt < 2; nt++) acc[mt][nt] = (f32x4){0.f, 0.f, 0.f, 0.f};

#define STAGE_W(t, buf)                                                      \
  {                                                                          \
    _Pragma("unroll")                                                        \
    for (int r = 0; r < 2; r++) {                                            \
      int id = tid + r * 256;                                                \
      int m = id >> 3, k4 = (id & 7) * 4;                                    \
      *(short4*)&wAh[buf][m * 40 + k4] =                                     \
          *(const short4*)&Wh[(size_t)(m0 + m) * 256 + (t) * 32 + k4];       \
      *(short4*)&wAl[buf][m * 40 + k4] =                                     \
          *(const short4*)&Wl[(size_t)(m0 + m) * 256 + (t) * 32 + k4];       \
    }                                                                        \
  }

  STAGE_W(0, 0);
  // B prologue: kstep 0
  bf16x8 cbh[2], cbl[2];
#pragma unroll
  for (int nt = 0; nt < 2; nt++) {
    size_t off = (size_t)(nt * 16 + lr) * 256 + lg * 8;
    cbh[nt] = *(const bf16x8*)&xbh[off];
    cbl[nt] = *(const bf16x8*)&xbl[off];
  }
  __syncthreads();

  for (int t = 0; t < 8; t++) {
    int buf = t & 1;
    if (t < 7) STAGE_W(t + 1, buf ^ 1);

    // prefetch next-kstep B fragments (global, independent of LDS bufs)
    bf16x8 nbh[2], nbl[2];
    if (t < 7) {
#pragma unroll
      for (int nt = 0; nt < 2; nt++) {
        size_t off = (size_t)(nt * 16 + lr) * 256 + (t + 1) * 32 + lg * 8;
        nbh[nt] = *(const bf16x8*)&xbh[off];
        nbl[nt] = *(const bf16x8*)&xbl[off];
      }
    } else {
#pragma unroll
      for (int nt = 0; nt < 2; nt++) { nbh[nt] = zv; nbl[nt] = zv; }
    }

    // A fragments from LDS
    bf16x8 ah[4], al[4];
#pragma unroll
    for (int mt = 0; mt < 4; mt++) {
      ah[mt] = *(const bf16x8*)&wAh[buf][(mt * 16 + lr) * 40 + lg * 8];
      al[mt] = *(const bf16x8*)&wAl[buf][(mt * 16 + lr) * 40 + lg * 8];
    }
#pragma unroll
    for (int mt = 0; mt < 4; mt++)
#pragma unroll
      for (int nt = 0; nt < 2; nt++) {
        acc[mt][nt] = __builtin_amdgcn_mfma_f32_16x16x32_bf16(ah[mt], cbh[nt], acc[mt][nt], 0, 0, 0);
        acc[mt][nt] = __builtin_amdgcn_mfma_f32_16x16x32_bf16(ah[mt], cbl[nt], acc[mt][nt], 0, 0, 0);
        acc[mt][nt] = __builtin_amdgcn_mfma_f32_16x16x32_bf16(al[mt], cbh[nt], acc[mt][nt], 0, 0, 0);
      }
    __syncthreads();
#pragma unroll
    for (int nt = 0; nt < 2; nt++) { cbh[nt] = nbh[nt]; cbl[nt] = nbl[nt]; }
  }

  // epilogue: D col = lane&15 (s), row = lg*4+reg (m)
  float* ob = Out + (size_t)b * M * S_;
#pragma unroll
  for (int mt = 0; mt < 4; mt++) {
    float4 b4 = *(const float4*)&bias[m0 + mt * 16 + lg * 4];
    float bv[4] = {b4.x, b4.y, b4.z, b4.w};
#pragma unroll
    for (int nt = 0; nt < 2; nt++) {
      int s = n0 + wv * 32 + nt * 16 + lr;
#pragma unroll
      for (int r = 0; r < 4; r++) {
        int m = m0 + mt * 16 + lg * 4 + r;
        ob[(size_t)m * S_ + s] = acc[mt][nt][r] + bv[r];
      }
    }
  }
#undef STAGE_W
}

// ---------------------------------------------------------------------------
// Row attention: per (b,n,h): S[i,w] = SCALE*sum_d rq[d,i,w]*rk[d,h,w],
// softmax over i (columns), store transposed bf16: arT[b,n,h][w][i].
// ---------------------------------------------------------------------------
__global__ __launch_bounds__(256) void row_attn_kernel(
    const float* __restrict__ rcv, u16* __restrict__ arT)
{
  __shared__ u16  rq[16 * 2304];     // [d][i*48+w]  73728 B
  __shared__ float rk[16 * 48];
  __shared__ float Sm[48 * 49];      // [i][w] padded
  __shared__ float cmax[48], crs[48];
  const int hg = blockIdx.x, n = blockIdx.y, b = blockIdx.z;
  const float* base = rcv + ((size_t)b * 768 + n * 96) * S_;  // rq; rk at +16*S_
  const int tid = threadIdx.x;

  for (int id = tid; id < 9216; id += 256) {     // 16*2304/4 float4s
    float4 v = *(const float4*)&base[id * 4];
    short4 s;
    s.x = (short)f2bf(v.x); s.y = (short)f2bf(v.y);
    s.z = (short)f2bf(v.z); s.w = (short)f2bf(v.w);
    *(short4*)&rq[id * 4] = s;
  }

  for (int hh = 0; hh < 6; hh++) {
    int h = hg * 6 + hh;
    for (int id = tid; id < 768; id += 256) {
      int d = id / 48, w = id % 48;
      rk[id] = base[(size_t)(16 + d) * S_ + h * 48 + w];
    }
    __syncthreads();
    for (int id = tid; id < 2304; id += 256) {
      int i = id / 48, w = id % 48;
      float s = 0.f;
#pragma unroll
      for (int d = 0; d < 16; d++)
        s += bf2f(rq[d * 2304 + i * 48 + w]) * rk[d * 48 + w];
      Sm[i * 49 + w] = s * 0.25f;
    }
    __syncthreads();
    if (tid < 48) {
      int w = tid;
      float m = -1e30f;
      for (int i = 0; i < 48; i++) m = fmaxf(m, Sm[i * 49 + w]);
      float s = 0.f;
      for (int i = 0; i < 48; i++) s += __expf(Sm[i * 49 + w] - m);
      cmax[w] = m; crs[w] = 1.0f / s;
    }
    __syncthreads();
    u16* dst = arT + ((size_t)(b * 8 + n) * 48 + h) * 2304;
    for (int id = tid; id < 2304; id += 256) {
      int w = id / 48, i = id % 48;
      float p = __expf(Sm[i * 49 + w] - cmax[w]) * crs[w];
      dst[id] = f2bf(p);                  // layout [w][i]
    }
    __syncthreads();
  }
}

// ---------------------------------------------------------------------------
// Col attention: per (b,n,h): T[w,j] = SCALE*sum_d ck[d,h,w]*cq[d,h,j],
// softmax over j (rows), store bf16: awT[b,n,h][w][j].
// ---------------------------------------------------------------------------
__global__ __launch_bounds__(256) void col_attn_kernel(
    const float* __restrict__ rcv, u16* __restrict__ awT)
{
  __shared__ float cq[16 * 48], ck[16 * 48];
  __shared__ float Tm[48 * 49];
  __shared__ float rmax[48], rrs[48];
  const int hg = blockIdx.x, n = blockIdx.y, b = blockIdx.z;
  const float* base = rcv + ((size_t)b * 768 + n * 96 + 32) * S_; // cq; ck at +16*S_
  const int tid = threadIdx.x;

  for (int hh = 0; hh < 6; hh++) {
    int h = hg * 6 + hh;
    for (int id = tid; id < 768; id += 256) {
      int d = id / 48, j = id % 48;
      cq[id] = base[(size_t)d * S_ + h * 48 + j];
      ck[id] = base[(size_t)(16 + d) * S_ + h * 48 + j];
    }
    __syncthreads();
    for (int id = tid; id < 2304; id += 256) {
      int w = id / 48, j = id % 48;
      float t = 0.f;
#pragma unroll
      for (int d = 0; d < 16; d++)
        t += ck[d * 48 + w] * cq[d * 48 + j];
      Tm[w * 49 + j] = t * 0.25f;
    }
    __syncthreads();
    if (tid < 48) {
      int w = tid;
      float m = -1e30f;
      for (int j = 0; j < 48; j++) m = fmaxf(m, Tm[w * 49 + j]);
      float s = 0.f;
      for (int j = 0; j < 48; j++) s += __expf(Tm[w * 49 + j] - m);
      rmax[w] = m; rrs[w] = 1.0f / s;
    }
    __syncthreads();
    u16* dst = awT + ((size_t)(b * 8 + n) * 48 + h) * 2304;
    for (int id = tid; id < 2304; id += 256) {
      int w = id / 48, j = id % 48;
      float p = __expf(Tm[w * 49 + j] - rmax[w]) * rrs[w];
      dst[id] = f2bf(p);                  // layout [w][j]
    }
    __syncthreads();
  }
}

// ---------------------------------------------------------------------------
// Main contraction + PE conv, wave-independent + software-pipelined:
// aw B-fragments prefetched one h ahead (global->reg); ar loads issued at
// top of body; setprio around MFMA cluster. NO min-waves spec: the r6
// __launch_bounds__(256,4) capped VGPR at 64 and spilled ~29 MB/dispatch
// to scratch (FETCH 11.5->48 MB, WRITE 9.2->38 MB, dur 43->92 us).
// Natural allocation (~110-128 VGPR) keeps 4 blocks/CU without spill.
// ---------------------------------------------------------------------------
__global__ __launch_bounds__(256) void attn_main_kernel(
    const float* __restrict__ rcv, const u16* __restrict__ arT,
    const u16* __restrict__ awT, const float* __restrict__ pe_w,
    const float* __restrict__ pe_b, float* __restrict__ y)
{
  __shared__ u16 vA[192 * 72];        // 27648 B  [(dloc,i)][j pad]
  const int id0 = blockIdx.x;
  const int n = id0 & 7;              // XCD swizzle
  const int rest = id0 >> 3;          // 0..127
  const int b = rest >> 5;            // 0..3
  const int inner = rest & 31;        // 0..31
  const int dchunk = inner >> 2;      // 0..7
  const int hc = inner & 3;           // 0..3
  const int h0 = hc * 12;
  const int tid = threadIdx.x;
  const int wave = tid >> 6, lane = tid & 63;
  const int lr = lane & 15, lg = lane >> 4;

  for (int id = tid; id < 192 * 24; id += 256) {
    int row = id / 24, col = 48 + id % 24;
    vA[row * 72 + col] = 0;
  }
  const float* vbase = rcv + ((size_t)b * 768 + n * 96 + 64 + dchunk * 4) * S_;
  for (int id = tid; id < 2304; id += 256) {   // 4 planes * 576 float4
    int dl = id / 576, rem = id % 576;
    int i = rem / 12, j4 = (rem % 12) * 4;
    float4 v = *(const float4*)&vbase[(size_t)dl * S_ + i * 48 + j4];
    short4 s;
    s.x = (short)f2bf(v.x); s.y = (short)f2bf(v.y);
    s.z = (short)f2bf(v.z); s.w = (short)f2bf(v.w);
    *(short4*)&vA[(dl * 48 + i) * 72 + j4] = s;
  }
  __syncthreads();   // the only barrier

  const size_t bnh0 = ((size_t)(b * 8 + n) * 48) * 2304;
  const int c = n * 32 + dchunk * 4 + wave;
  float pw[9];
#pragma unroll
  for (int t = 0; t < 9; t++) pw[t] = pe_w[c * 9 + t];
  const float pb = pe_b[c];
  float* yg = y + ((size_t)b * 256 + c) * S_;
  const int vrow0 = wave * 48;
  const bf16x8 zv = {0, 0, 0, 0, 0, 0, 0, 0};

  // prologue: aw fragments for h0
  bf16x8 cb0[3], cb1[3];
  {
    const u16* aw0 = awT + bnh0 + (size_t)h0 * 2304;
#pragma unroll
    for (int nt = 0; nt < 3; nt++) {
      int row = (nt * 16 + lr) * 48;
      cb0[nt] = *(const bf16x8*)&aw0[row + lg * 8];
      cb1[nt] = (lg < 2) ? *(const bf16x8*)&aw0[row + 32 + lg * 8] : zv;
    }
  }

  for (int hh = 0; hh < 12; hh++) {
    const int h = h0 + hh;
    const u16* arg = arT + bnh0 + (size_t)h * 2304;  // [w][i]

    // issue all ar loads now (consumed after the MFMA block)
    short4 sar[3][3];
#pragma unroll
    for (int nt = 0; nt < 3; nt++)
#pragma unroll
      for (int mt = 0; mt < 3; mt++)
        sar[nt][mt] = *(const short4*)&arg[(nt * 16 + lr) * 48 + mt * 16 + lg * 4];

    // prefetch next-h aw fragments (consumed next iteration)
    bf16x8 nb0[3], nb1[3];
    if (hh < 11) {
      const u16* awn = awT + bnh0 + (size_t)(h + 1) * 2304;
#pragma unroll
      for (int nt = 0; nt < 3; nt++) {
        int row = (nt * 16 + lr) * 48;
        nb0[nt] = *(const bf16x8*)&awn[row + lg * 8];
        nb1[nt] = (lg < 2) ? *(const bf16x8*)&awn[row + 32 + lg * 8] : zv;
      }
    } else {
#pragma unroll
      for (int nt = 0; nt < 3; nt++) { nb0[nt] = zv; nb1[nt] = zv; }
    }

    f32x4 acc[3][3];
#pragma unroll
    for (int mt = 0; mt < 3; mt++)
#pragma unroll
      for (int nt = 0; nt < 3; nt++) acc[mt][nt] = (f32x4){0.f, 0.f, 0.f, 0.f};

    __builtin_amdgcn_s_setprio(1);
#pragma unroll
    for (int mt = 0; mt < 3; mt++) {
      bf16x8 a0 = *(const bf16x8*)&vA[(vrow0 + mt * 16 + lr) * 72 + lg * 8];
      bf16x8 a1 = *(const bf16x8*)&vA[(vrow0 + mt * 16 + lr) * 72 + 32 + lg * 8];
#pragma unroll
      for (int nt = 0; nt < 3; nt++) {
        acc[mt][nt] = __builtin_amdgcn_mfma_f32_16x16x32_bf16(a0, cb0[nt], acc[mt][nt], 0, 0, 0);
        acc[mt][nt] = __builtin_amdgcn_mfma_f32_16x16x32_bf16(a1, cb1[nt], acc[mt][nt], 0, 0, 0);
      }
    }
    __builtin_amdgcn_s_setprio(0);

    float pv[3];
#pragma unroll
    for (int nt = 0; nt < 3; nt++) {
      float p = 0.f;
#pragma unroll
      for (int mt = 0; mt < 3; mt++) {
        short4 s = sar[nt][mt];
        p += bf2f((u16)s.x) * acc[mt][nt][0] + bf2f((u16)s.y) * acc[mt][nt][1]
           + bf2f((u16)s.z) * acc[mt][nt][2] + bf2f((u16)s.w) * acc[mt][nt][3];
      }
      p += __shfl_xor(p, 16);
      p += __shfl_xor(p, 32);
      pv[nt] = p;
    }

    if (lane < 48) {
      float a = (lane < 16) ? pv[0] : (lane < 32 ? pv[1] : pv[2]);
      a += pb;
      int ww = lane;
#pragma unroll
      for (int kh = -1; kh <= 1; kh++) {
        int ih = h + kh;
        if (ih < 0 || ih > 47) continue;
#pragma unroll
        for (int kw = -1; kw <= 1; kw++) {
          int jw = ww + kw;
          if (jw < 0 || jw > 47) continue;
          a += pw[(kh + 1) * 3 + (kw + 1)] * bf2f(vA[(vrow0 + ih) * 72 + jw]);
        }
      }
      yg[h * 48 + ww] = a;
    }

    // rotate prefetched aw fragments
#pragma unroll
    for (int nt = 0; nt < 3; nt++) { cb0[nt] = nb0[nt]; cb1[nt] = nb1[nt]; }
  }
}

// ---------------------------------------------------------------------------
extern "C" void kernel_launch(void* const* d_in, const int* in_sizes, int n_in,
                              void* d_out, int out_size, void* d_ws, size_t ws_size,
                              hipStream_t stream) {
  const float* x      = (const float*)d_in[0];
  const float* rcv_w  = (const float*)d_in[1];
  const float* rcv_b  = (const float*)d_in[2];
  const float* pe_w   = (const float*)d_in[3];
  const float* pe_b   = (const float*)d_in[4];
  const float* proj_w = (const float*)d_in[5];
  const float* proj_b = (const float*)d_in[6];
  float* out = (float*)d_out;

  char* ws = (char*)d_ws;
  float* rcv = (float*)ws;                         // 28,311,552 B
  u16*   arT = (u16*)(ws + 28311552);              //  7,077,888 B
  u16*   awT = (u16*)(ws + 35389440);              //  7,077,888 B
  float* y   = (float*)(ws + 42467328);            //  9,437,184 B
  u16*   xTh = (u16*)(ws + 51904512);              //  4,718,592 B
  u16*   xTl = (u16*)(ws + 56623104);              //  4,718,592 B
  u16*   Whr = (u16*)(ws + 61341696);              //    393,216 B
  u16*   Wlr = (u16*)(ws + 61734912);              //    393,216 B
  u16*   Whp = (u16*)(ws + 62128128);              //    131,072 B
  u16*   Wlp = (u16*)(ws + 62259200);              //    131,072 B
  // yT aliases arT/awT region (free after attn_main)
  u16*   yTh = arT;
  u16*   yTl = awT;

  splitw_kernel<<<dim3(192), 256, 0, stream>>>(rcv_w, Whr, Wlr);
  splitw_kernel<<<dim3(64),  256, 0, stream>>>(proj_w, Whp, Wlp);
  split_transpose_kernel<<<dim3(36, 4, 4), 256, 0, stream>>>(x, xTh, xTl);
  gemm_mfma_kernel<<<dim3(72 * 12), 256, 0, stream>>>(Whr, Wlr, rcv_b, xTh, xTl, rcv, 768);
  row_attn_kernel<<<dim3(8, 8, 4), 256, 0, stream>>>(rcv, arT);
  col_attn_kernel<<<dim3(8, 8, 4), 256, 0, stream>>>(rcv, awT);
  attn_main_kernel<<<dim3(1024), 256, 0, stream>>>(rcv, arT, awT, pe_w, pe_b, y);
  split_transpose_kernel<<<dim3(36, 4, 4), 256, 0, stream>>>(y, yTh, yTl);
  gemm_mfma_kernel<<<dim3(72 * 4), 256, 0, stream>>>(Whp, Wlp, proj_b, yTh, yTl, out, 256);
}

// Round 8
// 164.405 us; speedup vs baseline: 1.2541x; 1.1010x over previous
//
#include <hip/hip_runtime.h>

#define S_ 2304   // 48*48

typedef unsigned short u16;
typedef __attribute__((ext_vector_type(8))) short bf16x8;
typedef __attribute__((ext_vector_type(4))) float f32x4;

static __device__ __forceinline__ u16 f2bf(float x) {
  union { float f; unsigned u; } v; v.f = x;
  unsigned r = v.u + 0x7FFFu + ((v.u >> 16) & 1u);
  return (u16)(r >> 16);
}
static __device__ __forceinline__ float bf2f(u16 h) {
  union { unsigned u; float f; } v; v.u = ((unsigned)h) << 16; return v.f;
}

// ---------------------------------------------------------------------------
// Weight split: fp32 -> bf16 hi + bf16 lo(residual). n multiple of 1024.
// ---------------------------------------------------------------------------
__global__ __launch_bounds__(256) void splitw_kernel(
    const float* __restrict__ w, u16* __restrict__ wh, u16* __restrict__ wl)
{
  int id = blockIdx.x * 256 + threadIdx.x;
  float4 v = ((const float4*)w)[id];
  short4 h, l;
  float f[4] = {v.x, v.y, v.z, v.w};
  u16 hh[4], ll[4];
#pragma unroll
  for (int q = 0; q < 4; q++) {
    hh[q] = f2bf(f[q]);
    ll[q] = f2bf(f[q] - bf2f(hh[q]));
  }
  h.x = hh[0]; h.y = hh[1]; h.z = hh[2]; h.w = hh[3];
  l.x = ll[0]; l.y = ll[1]; l.z = ll[2]; l.w = ll[3];
  ((short4*)wh)[id] = h;
  ((short4*)wl)[id] = l;
}

// ---------------------------------------------------------------------------
// Split-transpose: in[b][256][2304] fp32 -> outh/outl[b][2304][256] bf16 h/l.
// 64x64 tiles via LDS (u32-packed h|l). Grid (36, 4, 4b).
// ---------------------------------------------------------------------------
__global__ __launch_bounds__(256) void split_transpose_kernel(
    const float* __restrict__ in, u16* __restrict__ outh, u16* __restrict__ outl)
{
  __shared__ unsigned tile[64][65];
  const int s0 = blockIdx.x * 64, c0 = blockIdx.y * 64, b = blockIdx.z;
  const float* inb = in + (size_t)b * 256 * S_;
  u16* oh = outh + (size_t)b * S_ * 256;
  u16* ol = outl + (size_t)b * S_ * 256;
  const int tid = threadIdx.x;
#pragma unroll
  for (int it = 0; it < 4; it++) {
    int id = tid + it * 256;
    int c = id >> 4, s4 = (id & 15) * 4;
    float4 v = *(const float4*)&inb[(size_t)(c0 + c) * S_ + s0 + s4];
    float f[4] = {v.x, v.y, v.z, v.w};
#pragma unroll
    for (int q = 0; q < 4; q++) {
      u16 h = f2bf(f[q]);
      u16 l = f2bf(f[q] - bf2f(h));
      tile[s4 + q][c] = (unsigned)h | ((unsigned)l << 16);
    }
  }
  __syncthreads();
#pragma unroll
  for (int it = 0; it < 4; it++) {
    int id = tid + it * 256;
    int s = id >> 4, c4 = (id & 15) * 4;
    short4 h, l;
    unsigned p0 = tile[s][c4 + 0], p1 = tile[s][c4 + 1];
    unsigned p2 = tile[s][c4 + 2], p3 = tile[s][c4 + 3];
    h.x = (short)(p0 & 0xffff); h.y = (short)(p1 & 0xffff);
    h.z = (short)(p2 & 0xffff); h.w = (short)(p3 & 0xffff);
    l.x = (short)(p0 >> 16); l.y = (short)(p1 >> 16);
    l.z = (short)(p2 >> 16); l.w = (short)(p3 >> 16);
    *(short4*)&oh[(size_t)(s0 + s) * 256 + c0 + c4] = h;
    *(short4*)&ol[(size_t)(s0 + s) * 256 + c0 + c4] = l;
  }
}

// ---------------------------------------------------------------------------
// MFMA split-bf16 GEMM with B-prefetch pipeline (unchanged from r7).
// ---------------------------------------------------------------------------
__global__ __launch_bounds__(256) void gemm_mfma_kernel(
    const u16* __restrict__ Wh, const u16* __restrict__ Wl,
    const float* __restrict__ bias,
    const u16* __restrict__ XTh, const u16* __restrict__ XTl,
    float* __restrict__ Out, int M)
{
  __shared__ u16 wAh[2][64 * 40];   // 5120 B per buf
  __shared__ u16 wAl[2][64 * 40];
  const int MB = M >> 6;
  const int xcd = blockIdx.x & 7;
  const int idx = blockIdx.x >> 3;          // 0 .. 9*MB-1
  const int g = xcd * 9 + idx / MB;         // 0..71 group = (n_blk, b)
  const int mb = idx % MB;
  const int nb = g % 18, b = g / 18;
  const int m0 = mb * 64, n0 = nb * 128;
  const int tid = threadIdx.x;
  const int wv = tid >> 6, lane = tid & 63;
  const int lr = lane & 15, lg = lane >> 4;
  const bf16x8 zv = {0, 0, 0, 0, 0, 0, 0, 0};

  const u16* xbh = XTh + ((size_t)b * S_ + n0 + wv * 32) * 256;
  const u16* xbl = XTl + ((size_t)b * S_ + n0 + wv * 32) * 256;

  f32x4 acc[4][2];
#pragma unroll
  for (int mt = 0; mt < 4; mt++)
#pragma unroll
    for (int nt = 0; nt < 2; nt++) acc[mt][nt] = (f32x4){0.f, 0.f, 0.f, 0.f};

#define STAGE_W(t, buf)                                                      \
  {                                                                          \
    _Pragma("unroll")                                                        \
    for (int r = 0; r < 2; r++) {                                            \
      int id = tid + r * 256;                                                \
      int m = id >> 3, k4 = (id & 7) * 4;                                    \
      *(short4*)&wAh[buf][m * 40 + k4] =                                     \
          *(const short4*)&Wh[(size_t)(m0 + m) * 256 + (t) * 32 + k4];       \
      *(short4*)&wAl[buf][m * 40 + k4] =                                     \
          *(const short4*)&Wl[(size_t)(m0 + m) * 256 + (t) * 32 + k4];       \
    }                                                                        \
  }

  STAGE_W(0, 0);
  // B prologue: kstep 0
  bf16x8 cbh[2], cbl[2];
#pragma unroll
  for (int nt = 0; nt < 2; nt++) {
    size_t off = (size_t)(nt * 16 + lr) * 256 + lg * 8;
    cbh[nt] = *(const bf16x8*)&xbh[off];
    cbl[nt] = *(const bf16x8*)&xbl[off];
  }
  __syncthreads();

  for (int t = 0; t < 8; t++) {
    int buf = t & 1;
    if (t < 7) STAGE_W(t + 1, buf ^ 1);

    // prefetch next-kstep B fragments (global, independent of LDS bufs)
    bf16x8 nbh[2], nbl[2];
    if (t < 7) {
#pragma unroll
      for (int nt = 0; nt < 2; nt++) {
        size_t off = (size_t)(nt * 16 + lr) * 256 + (t + 1) * 32 + lg * 8;
        nbh[nt] = *(const bf16x8*)&xbh[off];
        nbl[nt] = *(const bf16x8*)&xbl[off];
      }
    } else {
#pragma unroll
      for (int nt = 0; nt < 2; nt++) { nbh[nt] = zv; nbl[nt] = zv; }
    }

    // A fragments from LDS
    bf16x8 ah[4], al[4];
#pragma unroll
    for (int mt = 0; mt < 4; mt++) {
      ah[mt] = *(const bf16x8*)&wAh[buf][(mt * 16 + lr) * 40 + lg * 8];
      al[mt] = *(const bf16x8*)&wAl[buf][(mt * 16 + lr) * 40 + lg * 8];
    }
#pragma unroll
    for (int mt = 0; mt < 4; mt++)
#pragma unroll
      for (int nt = 0; nt < 2; nt++) {
        acc[mt][nt] = __builtin_amdgcn_mfma_f32_16x16x32_bf16(ah[mt], cbh[nt], acc[mt][nt], 0, 0, 0);
        acc[mt][nt] = __builtin_amdgcn_mfma_f32_16x16x32_bf16(ah[mt], cbl[nt], acc[mt][nt], 0, 0, 0);
        acc[mt][nt] = __builtin_amdgcn_mfma_f32_16x16x32_bf16(al[mt], cbh[nt], acc[mt][nt], 0, 0, 0);
      }
    __syncthreads();
#pragma unroll
    for (int nt = 0; nt < 2; nt++) { cbh[nt] = nbh[nt]; cbl[nt] = nbl[nt]; }
  }

  // epilogue: D col = lane&15 (s), row = lg*4+reg (m)
  float* ob = Out + (size_t)b * M * S_;
#pragma unroll
  for (int mt = 0; mt < 4; mt++) {
    float4 b4 = *(const float4*)&bias[m0 + mt * 16 + lg * 4];
    float bv[4] = {b4.x, b4.y, b4.z, b4.w};
#pragma unroll
    for (int nt = 0; nt < 2; nt++) {
      int s = n0 + wv * 32 + nt * 16 + lr;
#pragma unroll
      for (int r = 0; r < 4; r++) {
        int m = m0 + mt * 16 + lg * 4 + r;
        ob[(size_t)m * S_ + s] = acc[mt][nt][r] + bv[r];
      }
    }
  }
#undef STAGE_W
}

// ---------------------------------------------------------------------------
// Row attention: per (b,n,h): S[i,w] = SCALE*sum_d rq[d,i,w]*rk[d,h,w],
// softmax over i (columns), store transposed bf16: arT[b,n,h][w][i].
// ---------------------------------------------------------------------------
__global__ __launch_bounds__(256) void row_attn_kernel(
    const float* __restrict__ rcv, u16* __restrict__ arT)
{
  __shared__ u16  rq[16 * 2304];     // [d][i*48+w]  73728 B
  __shared__ float rk[16 * 48];
  __shared__ float Sm[48 * 49];      // [i][w] padded
  __shared__ float cmax[48], crs[48];
  const int hg = blockIdx.x, n = blockIdx.y, b = blockIdx.z;
  const float* base = rcv + ((size_t)b * 768 + n * 96) * S_;  // rq; rk at +16*S_
  const int tid = threadIdx.x;

  for (int id = tid; id < 9216; id += 256) {     // 16*2304/4 float4s
    float4 v = *(const float4*)&base[id * 4];
    short4 s;
    s.x = (short)f2bf(v.x); s.y = (short)f2bf(v.y);
    s.z = (short)f2bf(v.z); s.w = (short)f2bf(v.w);
    *(short4*)&rq[id * 4] = s;
  }

  for (int hh = 0; hh < 6; hh++) {
    int h = hg * 6 + hh;
    for (int id = tid; id < 768; id += 256) {
      int d = id / 48, w = id % 48;
      rk[id] = base[(size_t)(16 + d) * S_ + h * 48 + w];
    }
    __syncthreads();
    for (int id = tid; id < 2304; id += 256) {
      int i = id / 48, w = id % 48;
      float s = 0.f;
#pragma unroll
      for (int d = 0; d < 16; d++)
        s += bf2f(rq[d * 2304 + i * 48 + w]) * rk[d * 48 + w];
      Sm[i * 49 + w] = s * 0.25f;
    }
    __syncthreads();
    if (tid < 48) {
      int w = tid;
      float m = -1e30f;
      for (int i = 0; i < 48; i++) m = fmaxf(m, Sm[i * 49 + w]);
      float s = 0.f;
      for (int i = 0; i < 48; i++) s += __expf(Sm[i * 49 + w] - m);
      cmax[w] = m; crs[w] = 1.0f / s;
    }
    __syncthreads();
    u16* dst = arT + ((size_t)(b * 8 + n) * 48 + h) * 2304;
    for (int id = tid; id < 2304; id += 256) {
      int w = id / 48, i = id % 48;
      float p = __expf(Sm[i * 49 + w] - cmax[w]) * crs[w];
      dst[id] = f2bf(p);                  // layout [w][i]
    }
    __syncthreads();
  }
}

// ---------------------------------------------------------------------------
// Col attention: per (b,n,h): T[w,j] = SCALE*sum_d ck[d,h,w]*cq[d,h,j],
// softmax over j (rows), store bf16: awT[b,n,h][w][j].
// ---------------------------------------------------------------------------
__global__ __launch_bounds__(256) void col_attn_kernel(
    const float* __restrict__ rcv, u16* __restrict__ awT)
{
  __shared__ float cq[16 * 48], ck[16 * 48];
  __shared__ float Tm[48 * 49];
  __shared__ float rmax[48], rrs[48];
  const int hg = blockIdx.x, n = blockIdx.y, b = blockIdx.z;
  const float* base = rcv + ((size_t)b * 768 + n * 96 + 32) * S_; // cq; ck at +16*S_
  const int tid = threadIdx.x;

  for (int hh = 0; hh < 6; hh++) {
    int h = hg * 6 + hh;
    for (int id = tid; id < 768; id += 256) {
      int d = id / 48, j = id % 48;
      cq[id] = base[(size_t)d * S_ + h * 48 + j];
      ck[id] = base[(size_t)(16 + d) * S_ + h * 48 + j];
    }
    __syncthreads();
    for (int id = tid; id < 2304; id += 256) {
      int w = id / 48, j = id % 48;
      float t = 0.f;
#pragma unroll
      for (int d = 0; d < 16; d++)
        t += ck[d * 48 + w] * cq[d * 48 + j];
      Tm[w * 49 + j] = t * 0.25f;
    }
    __syncthreads();
    if (tid < 48) {
      int w = tid;
      float m = -1e30f;
      for (int j = 0; j < 48; j++) m = fmaxf(m, Tm[w * 49 + j]);
      float s = 0.f;
      for (int j = 0; j < 48; j++) s += __expf(Tm[w * 49 + j] - m);
      rmax[w] = m; rrs[w] = 1.0f / s;
    }
    __syncthreads();
    u16* dst = awT + ((size_t)(b * 8 + n) * 48 + h) * 2304;
    for (int id = tid; id < 2304; id += 256) {
      int w = id / 48, j = id % 48;
      float p = __expf(Tm[w * 49 + j] - rmax[w]) * rrs[w];
      dst[id] = f2bf(p);                  // layout [w][j]
    }
    __syncthreads();
  }
}

// ---------------------------------------------------------------------------
// Main contraction + PE conv. r5 body (no prefetch/setprio — r6/r7 pipeline
// was a net loss), but occupancy-doubled decomposition:
//   2 v-planes per block (vA 13.8 KB), 4 waves = 2 planes x 2 h-halves
//   (6 h each). Grid 2048 blocks = 8 blocks/CU = 32 waves/CU.
// ---------------------------------------------------------------------------
__global__ __launch_bounds__(256) void attn_main_kernel(
    const float* __restrict__ rcv, const u16* __restrict__ arT,
    const u16* __restrict__ awT, const float* __restrict__ pe_w,
    const float* __restrict__ pe_b, float* __restrict__ y)
{
  __shared__ u16 vA[96 * 72];         // 13824 B  [(dloc,i)][j pad]
  const int id0 = blockIdx.x;
  const int n = id0 & 7;              // XCD swizzle
  const int rest = id0 >> 3;          // 0..255
  const int b = rest >> 6;            // 0..3
  const int inner = rest & 63;        // 0..63
  const int dchunk = inner >> 2;      // 0..15 (2 planes each)
  const int hc = inner & 3;           // 0..3
  const int tid = threadIdx.x;
  const int wave = tid >> 6, lane = tid & 63;
  const int dl = wave >> 1, half = wave & 1;
  const int h0 = hc * 12 + half * 6;
  const int lr = lane & 15, lg = lane >> 4;

  // zero only the j-pad columns (48..71); staging fills cols 0..47
  for (int id = tid; id < 96 * 24; id += 256) {
    int row = id / 24, col = 48 + id % 24;
    vA[row * 72 + col] = 0;
  }
  const float* vbase = rcv + ((size_t)b * 768 + n * 96 + 64 + dchunk * 2) * S_;
  for (int id = tid; id < 1152; id += 256) {   // 2 planes * 576 float4
    int dl2 = id / 576, rem = id % 576;
    int i = rem / 12, j4 = (rem % 12) * 4;
    float4 v = *(const float4*)&vbase[(size_t)dl2 * S_ + i * 48 + j4];
    short4 s;
    s.x = (short)f2bf(v.x); s.y = (short)f2bf(v.y);
    s.z = (short)f2bf(v.z); s.w = (short)f2bf(v.w);
    *(short4*)&vA[(dl2 * 48 + i) * 72 + j4] = s;
  }
  __syncthreads();   // the only barrier

  const size_t bnh0 = ((size_t)(b * 8 + n) * 48) * 2304;
  const int c = n * 32 + dchunk * 2 + dl;   // global channel of this wave's d-plane
  float pw[9];
#pragma unroll
  for (int t = 0; t < 9; t++) pw[t] = pe_w[c * 9 + t];
  const float pb = pe_b[c];
  float* yg = y + ((size_t)b * 256 + c) * S_;
  const int vrow0 = dl * 48;
  const bf16x8 zv = {0, 0, 0, 0, 0, 0, 0, 0};

  for (int hh = 0; hh < 6; hh++) {
    int h = h0 + hh;
    const u16* awg = awT + bnh0 + (size_t)h * 2304;  // [w][j], stride 48
    const u16* arg = arT + bnh0 + (size_t)h * 2304;  // [w][i], stride 48

    // B fragments direct from global: n=lr (w), k = lg*8+t
    bf16x8 bf0[3], bf1[3];
#pragma unroll
    for (int nt = 0; nt < 3; nt++) {
      int row = (nt * 16 + lr) * 48;
      bf0[nt] = *(const bf16x8*)&awg[row + lg * 8];                // j = 0..31
      bf1[nt] = (lg < 2) ? *(const bf16x8*)&awg[row + 32 + lg * 8] // j = 32..47
                         : zv;                                    // j >= 48 -> 0
    }

    f32x4 acc[3][3];
#pragma unroll
    for (int mt = 0; mt < 3; mt++)
#pragma unroll
      for (int nt = 0; nt < 3; nt++) acc[mt][nt] = (f32x4){0.f, 0.f, 0.f, 0.f};

#pragma unroll
    for (int mt = 0; mt < 3; mt++) {
      bf16x8 a0 = *(const bf16x8*)&vA[(vrow0 + mt * 16 + lr) * 72 + lg * 8];
      bf16x8 a1 = *(const bf16x8*)&vA[(vrow0 + mt * 16 + lr) * 72 + 32 + lg * 8];
#pragma unroll
      for (int nt = 0; nt < 3; nt++) {
        acc[mt][nt] = __builtin_amdgcn_mfma_f32_16x16x32_bf16(a0, bf0[nt], acc[mt][nt], 0, 0, 0);
        acc[mt][nt] = __builtin_amdgcn_mfma_f32_16x16x32_bf16(a1, bf1[nt], acc[mt][nt], 0, 0, 0);
      }
    }

    // contract i with ar (direct global 8B reads), reduce over lane groups
    float pv[3];
#pragma unroll
    for (int nt = 0; nt < 3; nt++) {
      int wrow = (nt * 16 + lr) * 48;
      float p = 0.f;
#pragma unroll
      for (int mt = 0; mt < 3; mt++) {
        short4 s = *(const short4*)&arg[wrow + mt * 16 + lg * 4];
        p += bf2f((u16)s.x) * acc[mt][nt][0] + bf2f((u16)s.y) * acc[mt][nt][1]
           + bf2f((u16)s.z) * acc[mt][nt][2] + bf2f((u16)s.w) * acc[mt][nt][3];
      }
      p += __shfl_xor(p, 16);
      p += __shfl_xor(p, 32);
      pv[nt] = p;             // all lanes: value for w = nt*16 + lr
    }

    // lanes 0..47 write w=lane: PE depthwise 3x3 from resident v + store
    if (lane < 48) {
      float a = (lane < 16) ? pv[0] : (lane < 32 ? pv[1] : pv[2]);
      a += pb;
      int ww = lane;
#pragma unroll
      for (int kh = -1; kh <= 1; kh++) {
        int ih = h + kh;
        if (ih < 0 || ih > 47) continue;
#pragma unroll
        for (int kw = -1; kw <= 1; kw++) {
          int jw = ww + kw;
          if (jw < 0 || jw > 47) continue;
          a += pw[(kh + 1) * 3 + (kw + 1)] * bf2f(vA[(vrow0 + ih) * 72 + jw]);
        }
      }
      yg[h * 48 + ww] = a;
    }
  }
}

// ---------------------------------------------------------------------------
extern "C" void kernel_launch(void* const* d_in, const int* in_sizes, int n_in,
                              void* d_out, int out_size, void* d_ws, size_t ws_size,
                              hipStream_t stream) {
  const float* x      = (const float*)d_in[0];
  const float* rcv_w  = (const float*)d_in[1];
  const float* rcv_b  = (const float*)d_in[2];
  const float* pe_w   = (const float*)d_in[3];
  const float* pe_b   = (const float*)d_in[4];
  const float* proj_w = (const float*)d_in[5];
  const float* proj_b = (const float*)d_in[6];
  float* out = (float*)d_out;

  char* ws = (char*)d_ws;
  float* rcv = (float*)ws;                         // 28,311,552 B
  u16*   arT = (u16*)(ws + 28311552);              //  7,077,888 B
  u16*   awT = (u16*)(ws + 35389440);              //  7,077,888 B
  float* y   = (float*)(ws + 42467328);            //  9,437,184 B
  u16*   xTh = (u16*)(ws + 51904512);              //  4,718,592 B
  u16*   xTl = (u16*)(ws + 56623104);              //  4,718,592 B
  u16*   Whr = (u16*)(ws + 61341696);              //    393,216 B
  u16*   Wlr = (u16*)(ws + 61734912);              //    393,216 B
  u16*   Whp = (u16*)(ws + 62128128);              //    131,072 B
  u16*   Wlp = (u16*)(ws + 62259200);              //    131,072 B
  // yT aliases arT/awT region (free after attn_main)
  u16*   yTh = arT;
  u16*   yTl = awT;

  splitw_kernel<<<dim3(192), 256, 0, stream>>>(rcv_w, Whr, Wlr);
  splitw_kernel<<<dim3(64),  256, 0, stream>>>(proj_w, Whp, Wlp);
  split_transpose_kernel<<<dim3(36, 4, 4), 256, 0, stream>>>(x, xTh, xTl);
  gemm_mfma_kernel<<<dim3(72 * 12), 256, 0, stream>>>(Whr, Wlr, rcv_b, xTh, xTl, rcv, 768);
  row_attn_kernel<<<dim3(8, 8, 4), 256, 0, stream>>>(rcv, arT);
  col_attn_kernel<<<dim3(8, 8, 4), 256, 0, stream>>>(rcv, awT);
  attn_main_kernel<<<dim3(2048), 256, 0, stream>>>(rcv, arT, awT, pe_w, pe_b, y);
  split_transpose_kernel<<<dim3(36, 4, 4), 256, 0, stream>>>(y, yTh, yTl);
  gemm_mfma_kernel<<<dim3(72 * 4), 256, 0, stream>>>(Whp, Wlp, proj_b, yTh, yTl, out, 256);
}

// Round 9
// 159.436 us; speedup vs baseline: 1.2932x; 1.0312x over previous
//
#include <hip/hip_runtime.h>

#define S_ 2304   // 48*48

typedef unsigned short u16;
typedef __attribute__((ext_vector_type(8))) short bf16x8;
typedef __attribute__((ext_vector_type(4))) float f32x4;

static __device__ __forceinline__ u16 f2bf(float x) {
  union { float f; unsigned u; } v; v.f = x;
  unsigned r = v.u + 0x7FFFu + ((v.u >> 16) & 1u);
  return (u16)(r >> 16);
}
static __device__ __forceinline__ float bf2f(u16 h) {
  union { unsigned u; float f; } v; v.u = ((unsigned)h) << 16; return v.f;
}

// ---------------------------------------------------------------------------
// Weight split: fp32 -> bf16 hi + bf16 lo(residual). n multiple of 1024.
// ---------------------------------------------------------------------------
__global__ __launch_bounds__(256) void splitw_kernel(
    const float* __restrict__ w, u16* __restrict__ wh, u16* __restrict__ wl)
{
  int id = blockIdx.x * 256 + threadIdx.x;
  float4 v = ((const float4*)w)[id];
  short4 h, l;
  float f[4] = {v.x, v.y, v.z, v.w};
  u16 hh[4], ll[4];
#pragma unroll
  for (int q = 0; q < 4; q++) {
    hh[q] = f2bf(f[q]);
    ll[q] = f2bf(f[q] - bf2f(hh[q]));
  }
  h.x = hh[0]; h.y = hh[1]; h.z = hh[2]; h.w = hh[3];
  l.x = ll[0]; l.y = ll[1]; l.z = ll[2]; l.w = ll[3];
  ((short4*)wh)[id] = h;
  ((short4*)wl)[id] = l;
}

// ---------------------------------------------------------------------------
// Split-transpose: in[b][256][2304] fp32 -> outh/outl[b][2304][256] bf16 h/l.
// 64x64 tiles via LDS (u32-packed h|l). Grid (36, 4, 4b).
// ---------------------------------------------------------------------------
__global__ __launch_bounds__(256) void split_transpose_kernel(
    const float* __restrict__ in, u16* __restrict__ outh, u16* __restrict__ outl)
{
  __shared__ unsigned tile[64][65];
  const int s0 = blockIdx.x * 64, c0 = blockIdx.y * 64, b = blockIdx.z;
  const float* inb = in + (size_t)b * 256 * S_;
  u16* oh = outh + (size_t)b * S_ * 256;
  u16* ol = outl + (size_t)b * S_ * 256;
  const int tid = threadIdx.x;
#pragma unroll
  for (int it = 0; it < 4; it++) {
    int id = tid + it * 256;
    int c = id >> 4, s4 = (id & 15) * 4;
    float4 v = *(const float4*)&inb[(size_t)(c0 + c) * S_ + s0 + s4];
    float f[4] = {v.x, v.y, v.z, v.w};
#pragma unroll
    for (int q = 0; q < 4; q++) {
      u16 h = f2bf(f[q]);
      u16 l = f2bf(f[q] - bf2f(h));
      tile[s4 + q][c] = (unsigned)h | ((unsigned)l << 16);
    }
  }
  __syncthreads();
#pragma unroll
  for (int it = 0; it < 4; it++) {
    int id = tid + it * 256;
    int s = id >> 4, c4 = (id & 15) * 4;
    short4 h, l;
    unsigned p0 = tile[s][c4 + 0], p1 = tile[s][c4 + 1];
    unsigned p2 = tile[s][c4 + 2], p3 = tile[s][c4 + 3];
    h.x = (short)(p0 & 0xffff); h.y = (short)(p1 & 0xffff);
    h.z = (short)(p2 & 0xffff); h.w = (short)(p3 & 0xffff);
    l.x = (short)(p0 >> 16); l.y = (short)(p1 >> 16);
    l.z = (short)(p2 >> 16); l.w = (short)(p3 >> 16);
    *(short4*)&oh[(size_t)(s0 + s) * 256 + c0 + c4] = h;
    *(short4*)&ol[(size_t)(s0 + s) * 256 + c0 + c4] = l;
  }
}

// ---------------------------------------------------------------------------
// MFMA split-bf16 GEMM with B-prefetch pipeline (unchanged from r8).
// ---------------------------------------------------------------------------
__global__ __launch_bounds__(256) void gemm_mfma_kernel(
    const u16* __restrict__ Wh, const u16* __restrict__ Wl,
    const float* __restrict__ bias,
    const u16* __restrict__ XTh, const u16* __restrict__ XTl,
    float* __restrict__ Out, int M)
{
  __shared__ u16 wAh[2][64 * 40];   // 5120 B per buf
  __shared__ u16 wAl[2][64 * 40];
  const int MB = M >> 6;
  const int xcd = blockIdx.x & 7;
  const int idx = blockIdx.x >> 3;          // 0 .. 9*MB-1
  const int g = xcd * 9 + idx / MB;         // 0..71 group = (n_blk, b)
  const int mb = idx % MB;
  const int nb = g % 18, b = g / 18;
  const int m0 = mb * 64, n0 = nb * 128;
  const int tid = threadIdx.x;
  const int wv = tid >> 6, lane = tid & 63;
  const int lr = lane & 15, lg = lane >> 4;
  const bf16x8 zv = {0, 0, 0, 0, 0, 0, 0, 0};

  const u16* xbh = XTh + ((size_t)b * S_ + n0 + wv * 32) * 256;
  const u16* xbl = XTl + ((size_t)b * S_ + n0 + wv * 32) * 256;

  f32x4 acc[4][2];
#pragma unroll
  for (int mt = 0; mt < 4; mt++)
#pragma unroll
    for (int nt = 0; nt < 2; nt++) acc[mt][nt] = (f32x4){0.f, 0.f, 0.f, 0.f};

#define STAGE_W(t, buf)                                                      \
  {                                                                          \
    _Pragma("unroll")                                                        \
    for (int r = 0; r < 2; r++) {                                            \
      int id = tid + r * 256;                                                \
      int m = id >> 3, k4 = (id & 7) * 4;                                    \
      *(short4*)&wAh[buf][m * 40 + k4] =                                     \
          *(const short4*)&Wh[(size_t)(m0 + m) * 256 + (t) * 32 + k4];       \
      *(short4*)&wAl[buf][m * 40 + k4] =                                     \
          *(const short4*)&Wl[(size_t)(m0 + m) * 256 + (t) * 32 + k4];       \
    }                                                                        \
  }

  STAGE_W(0, 0);
  // B prologue: kstep 0
  bf16x8 cbh[2], cbl[2];
#pragma unroll
  for (int nt = 0; nt < 2; nt++) {
    size_t off = (size_t)(nt * 16 + lr) * 256 + lg * 8;
    cbh[nt] = *(const bf16x8*)&xbh[off];
    cbl[nt] = *(const bf16x8*)&xbl[off];
  }
  __syncthreads();

  for (int t = 0; t < 8; t++) {
    int buf = t & 1;
    if (t < 7) STAGE_W(t + 1, buf ^ 1);

    // prefetch next-kstep B fragments (global, independent of LDS bufs)
    bf16x8 nbh[2], nbl[2];
    if (t < 7) {
#pragma unroll
      for (int nt = 0; nt < 2; nt++) {
        size_t off = (size_t)(nt * 16 + lr) * 256 + (t + 1) * 32 + lg * 8;
        nbh[nt] = *(const bf16x8*)&xbh[off];
        nbl[nt] = *(const bf16x8*)&xbl[off];
      }
    } else {
#pragma unroll
      for (int nt = 0; nt < 2; nt++) { nbh[nt] = zv; nbl[nt] = zv; }
    }

    // A fragments from LDS
    bf16x8 ah[4], al[4];
#pragma unroll
    for (int mt = 0; mt < 4; mt++) {
      ah[mt] = *(const bf16x8*)&wAh[buf][(mt * 16 + lr) * 40 + lg * 8];
      al[mt] = *(const bf16x8*)&wAl[buf][(mt * 16 + lr) * 40 + lg * 8];
    }
#pragma unroll
    for (int mt = 0; mt < 4; mt++)
#pragma unroll
      for (int nt = 0; nt < 2; nt++) {
        acc[mt][nt] = __builtin_amdgcn_mfma_f32_16x16x32_bf16(ah[mt], cbh[nt], acc[mt][nt], 0, 0, 0);
        acc[mt][nt] = __builtin_amdgcn_mfma_f32_16x16x32_bf16(ah[mt], cbl[nt], acc[mt][nt], 0, 0, 0);
        acc[mt][nt] = __builtin_amdgcn_mfma_f32_16x16x32_bf16(al[mt], cbh[nt], acc[mt][nt], 0, 0, 0);
      }
    __syncthreads();
#pragma unroll
    for (int nt = 0; nt < 2; nt++) { cbh[nt] = nbh[nt]; cbl[nt] = nbl[nt]; }
  }

  // epilogue: D col = lane&15 (s), row = lg*4+reg (m)
  float* ob = Out + (size_t)b * M * S_;
#pragma unroll
  for (int mt = 0; mt < 4; mt++) {
    float4 b4 = *(const float4*)&bias[m0 + mt * 16 + lg * 4];
    float bv[4] = {b4.x, b4.y, b4.z, b4.w};
#pragma unroll
    for (int nt = 0; nt < 2; nt++) {
      int s = n0 + wv * 32 + nt * 16 + lr;
#pragma unroll
      for (int r = 0; r < 4; r++) {
        int m = m0 + mt * 16 + lg * 4 + r;
        ob[(size_t)m * S_ + s] = acc[mt][nt][r] + bv[r];
      }
    }
  }
#undef STAGE_W
}

// ---------------------------------------------------------------------------
// Row attention -> arF in FRAGMENT-MAJOR layout:
//   arF[(bn*48+h)*2304 + (nt*3+mt)*256 + lane*4 + e]
//     = softmax_i(S)[w = nt*16+(lane&15)][i = mt*16+(lane>>4)*4+e]
// so attn_main's ar loads are lane-consecutive 8B (coalesced).
// ---------------------------------------------------------------------------
__global__ __launch_bounds__(256) void row_attn_kernel(
    const float* __restrict__ rcv, u16* __restrict__ arF)
{
  __shared__ u16  rq[16 * 2304];     // [d][i*48+w]  73728 B
  __shared__ float rk[16 * 48];
  __shared__ float Sm[48 * 49];      // [i][w] padded
  __shared__ float cmax[48], crs[48];
  const int hg = blockIdx.x, n = blockIdx.y, b = blockIdx.z;
  const float* base = rcv + ((size_t)b * 768 + n * 96) * S_;  // rq; rk at +16*S_
  const int tid = threadIdx.x;

  for (int id = tid; id < 9216; id += 256) {     // 16*2304/4 float4s
    float4 v = *(const float4*)&base[id * 4];
    short4 s;
    s.x = (short)f2bf(v.x); s.y = (short)f2bf(v.y);
    s.z = (short)f2bf(v.z); s.w = (short)f2bf(v.w);
    *(short4*)&rq[id * 4] = s;
  }

  for (int hh = 0; hh < 6; hh++) {
    int h = hg * 6 + hh;
    for (int id = tid; id < 768; id += 256) {
      int d = id / 48, w = id % 48;
      rk[id] = base[(size_t)(16 + d) * S_ + h * 48 + w];
    }
    __syncthreads();
    for (int id = tid; id < 2304; id += 256) {
      int i = id / 48, w = id % 48;
      float s = 0.f;
#pragma unroll
      for (int d = 0; d < 16; d++)
        s += bf2f(rq[d * 2304 + i * 48 + w]) * rk[d * 48 + w];
      Sm[i * 49 + w] = s * 0.25f;
    }
    __syncthreads();
    if (tid < 48) {
      int w = tid;
      float m = -1e30f;
      for (int i = 0; i < 48; i++) m = fmaxf(m, Sm[i * 49 + w]);
      float s = 0.f;
      for (int i = 0; i < 48; i++) s += __expf(Sm[i * 49 + w] - m);
      cmax[w] = m; crs[w] = 1.0f / s;
    }
    __syncthreads();
    u16* dst = arF + ((size_t)(b * 8 + n) * 48 + h) * 2304;
    for (int id = tid; id < 576; id += 256) {   // one 8B fragment chunk each
      int nt = id / 192, rem = id % 192, mt = rem / 64, l = rem % 64;
      int w = nt * 16 + (l & 15);
      int i0 = mt * 16 + ((l >> 4) << 2);
      short4 o;
      o.x = (short)f2bf(__expf(Sm[(i0 + 0) * 49 + w] - cmax[w]) * crs[w]);
      o.y = (short)f2bf(__expf(Sm[(i0 + 1) * 49 + w] - cmax[w]) * crs[w]);
      o.z = (short)f2bf(__expf(Sm[(i0 + 2) * 49 + w] - cmax[w]) * crs[w]);
      o.w = (short)f2bf(__expf(Sm[(i0 + 3) * 49 + w] - cmax[w]) * crs[w]);
      *(short4*)&dst[id * 4] = o;   // coalesced: thread id writes dst+id*8B
    }
    __syncthreads();
  }
}

// ---------------------------------------------------------------------------
// Col attention -> awF in FRAGMENT-MAJOR layout (MFMA B-operand order):
//   awF[(bn*48+h)*3072 + (nt*2+ks)*512 + lane*8 + e]
//     = softmax_j(T)[w = nt*16+(lane&15)][j = ks*32+(lane>>4)*8+e], 0 if j>=48
// k-tail (j>=48) stored as zeros -> attn_main loads unconditional+coalesced.
// ---------------------------------------------------------------------------
__global__ __launch_bounds__(256) void col_attn_kernel(
    const float* __restrict__ rcv, u16* __restrict__ awF)
{
  __shared__ float cq[16 * 48], ck[16 * 48];
  __shared__ float Tm[48 * 49];
  __shared__ float rmax[48], rrs[48];
  const int hg = blockIdx.x, n = blockIdx.y, b = blockIdx.z;
  const float* base = rcv + ((size_t)b * 768 + n * 96 + 32) * S_; // cq; ck at +16*S_
  const int tid = threadIdx.x;

  for (int hh = 0; hh < 6; hh++) {
    int h = hg * 6 + hh;
    for (int id = tid; id < 768; id += 256) {
      int d = id / 48, j = id % 48;
      cq[id] = base[(size_t)d * S_ + h * 48 + j];
      ck[id] = base[(size_t)(16 + d) * S_ + h * 48 + j];
    }
    __syncthreads();
    for (int id = tid; id < 2304; id += 256) {
      int w = id / 48, j = id % 48;
      float t = 0.f;
#pragma unroll
      for (int d = 0; d < 16; d++)
        t += ck[d * 48 + w] * cq[d * 48 + j];
      Tm[w * 49 + j] = t * 0.25f;
    }
    __syncthreads();
    if (tid < 48) {
      int w = tid;
      float m = -1e30f;
      for (int j = 0; j < 48; j++) m = fmaxf(m, Tm[w * 49 + j]);
      float s = 0.f;
      for (int j = 0; j < 48; j++) s += __expf(Tm[w * 49 + j] - m);
      rmax[w] = m; rrs[w] = 1.0f / s;
    }
    __syncthreads();
    u16* dst = awF + ((size_t)(b * 8 + n) * 48 + h) * 3072;
    for (int id = tid; id < 384; id += 256) {   // one 16B fragment chunk each
      int nt = id / 128, rem = id % 128, ks = rem / 64, l = rem % 64;
      int w = nt * 16 + (l & 15);
      int j0 = ks * 32 + ((l >> 4) << 3);
      u16 t8[8];
#pragma unroll
      for (int e = 0; e < 8; e++) {
        int j = j0 + e;
        t8[e] = (j < 48) ? f2bf(__expf(Tm[w * 49 + j] - rmax[w]) * rrs[w]) : (u16)0;
      }
      short4 o0, o1;
      o0.x = (short)t8[0]; o0.y = (short)t8[1]; o0.z = (short)t8[2]; o0.w = (short)t8[3];
      o1.x = (short)t8[4]; o1.y = (short)t8[5]; o1.z = (short)t8[6]; o1.w = (short)t8[7];
      *(short4*)&dst[id * 8]     = o0;   // coalesced: thread id writes dst+id*16B
      *(short4*)&dst[id * 8 + 4] = o1;
    }
    __syncthreads();
  }
}

// ---------------------------------------------------------------------------
// Main contraction + PE conv. r8 decomposition (2048 blocks, 2 v-planes,
// 4 waves = 2 planes x 2 h-halves), but aw/ar read from FRAGMENT-MAJOR
// buffers: every inner-loop global load is lane-consecutive (1-2 cache
// lines per instruction instead of ~16-24 -> kills the VMEM request-rate
// ceiling diagnosed in r8).
// ---------------------------------------------------------------------------
__global__ __launch_bounds__(256) void attn_main_kernel(
    const float* __restrict__ rcv, const u16* __restrict__ arF,
    const u16* __restrict__ awF, const float* __restrict__ pe_w,
    const float* __restrict__ pe_b, float* __restrict__ y)
{
  __shared__ u16 vA[96 * 72];         // 13824 B  [(dloc,i)][j pad]
  const int id0 = blockIdx.x;
  const int n = id0 & 7;              // XCD swizzle
  const int rest = id0 >> 3;          // 0..255
  const int b = rest >> 6;            // 0..3
  const int inner = rest & 63;        // 0..63
  const int dchunk = inner >> 2;      // 0..15 (2 planes each)
  const int hc = inner & 3;           // 0..3
  const int tid = threadIdx.x;
  const int wave = tid >> 6, lane = tid & 63;
  const int dl = wave >> 1, half = wave & 1;
  const int h0 = hc * 12 + half * 6;
  const int lr = lane & 15, lg = lane >> 4;

  // zero only the j-pad columns (48..71); staging fills cols 0..47
  for (int id = tid; id < 96 * 24; id += 256) {
    int row = id / 24, col = 48 + id % 24;
    vA[row * 72 + col] = 0;
  }
  const float* vbase = rcv + ((size_t)b * 768 + n * 96 + 64 + dchunk * 2) * S_;
  for (int id = tid; id < 1152; id += 256) {   // 2 planes * 576 float4
    int dl2 = id / 576, rem = id % 576;
    int i = rem / 12, j4 = (rem % 12) * 4;
    float4 v = *(const float4*)&vbase[(size_t)dl2 * S_ + i * 48 + j4];
    short4 s;
    s.x = (short)f2bf(v.x); s.y = (short)f2bf(v.y);
    s.z = (short)f2bf(v.z); s.w = (short)f2bf(v.w);
    *(short4*)&vA[(dl2 * 48 + i) * 72 + j4] = s;
  }
  __syncthreads();   // the only barrier

  const size_t bn48 = (size_t)(b * 8 + n) * 48;
  const int c = n * 32 + dchunk * 2 + dl;   // global channel of this wave's d-plane
  float pw[9];
#pragma unroll
  for (int t = 0; t < 9; t++) pw[t] = pe_w[c * 9 + t];
  const float pb = pe_b[c];
  float* yg = y + ((size_t)b * 256 + c) * S_;
  const int vrow0 = dl * 48;

  for (int hh = 0; hh < 6; hh++) {
    int h = h0 + hh;
    const u16* awg = awF + (bn48 + h) * 3072;  // fragment-major
    const u16* arg = arF + (bn48 + h) * 2304;  // fragment-major

    // B fragments: lane-consecutive 16B loads (coalesced)
    bf16x8 bf0[3], bf1[3];
#pragma unroll
    for (int nt = 0; nt < 3; nt++) {
      bf0[nt] = *(const bf16x8*)&awg[nt * 1024 + lane * 8];        // ks=0: j 0..31
      bf1[nt] = *(const bf16x8*)&awg[nt * 1024 + 512 + lane * 8];  // ks=1: j 32..47|0
    }

    f32x4 acc[3][3];
#pragma unroll
    for (int mt = 0; mt < 3; mt++)
#pragma unroll
      for (int nt = 0; nt < 3; nt++) acc[mt][nt] = (f32x4){0.f, 0.f, 0.f, 0.f};

#pragma unroll
    for (int mt = 0; mt < 3; mt++) {
      bf16x8 a0 = *(const bf16x8*)&vA[(vrow0 + mt * 16 + lr) * 72 + lg * 8];
      bf16x8 a1 = *(const bf16x8*)&vA[(vrow0 + mt * 16 + lr) * 72 + 32 + lg * 8];
#pragma unroll
      for (int nt = 0; nt < 3; nt++) {
        acc[mt][nt] = __builtin_amdgcn_mfma_f32_16x16x32_bf16(a0, bf0[nt], acc[mt][nt], 0, 0, 0);
        acc[mt][nt] = __builtin_amdgcn_mfma_f32_16x16x32_bf16(a1, bf1[nt], acc[mt][nt], 0, 0, 0);
      }
    }

    // contract i with ar (lane-consecutive 8B loads), reduce over lane groups
    float pv[3];
#pragma unroll
    for (int nt = 0; nt < 3; nt++) {
      float p = 0.f;
#pragma unroll
      for (int mt = 0; mt < 3; mt++) {
        short4 s = *(const short4*)&arg[(nt * 3 + mt) * 256 + lane * 4];
        p += bf2f((u16)s.x) * acc[mt][nt][0] + bf2f((u16)s.y) * acc[mt][nt][1]
           + bf2f((u16)s.z) * acc[mt][nt][2] + bf2f((u16)s.w) * acc[mt][nt][3];
      }
      p += __shfl_xor(p, 16);
      p += __shfl_xor(p, 32);
      pv[nt] = p;             // all lanes: value for w = nt*16 + lr
    }

    // lanes 0..47 write w=lane: PE depthwise 3x3 from resident v + store
    if (lane < 48) {
      float a = (lane < 16) ? pv[0] : (lane < 32 ? pv[1] : pv[2]);
      a += pb;
      int ww = lane;
#pragma unroll
      for (int kh = -1; kh <= 1; kh++) {
        int ih = h + kh;
        if (ih < 0 || ih > 47) continue;
#pragma unroll
        for (int kw = -1; kw <= 1; kw++) {
          int jw = ww + kw;
          if (jw < 0 || jw > 47) continue;
          a += pw[(kh + 1) * 3 + (kw + 1)] * bf2f(vA[(vrow0 + ih) * 72 + jw]);
        }
      }
      yg[h * 48 + ww] = a;
    }
  }
}

// ---------------------------------------------------------------------------
extern "C" void kernel_launch(void* const* d_in, const int* in_sizes, int n_in,
                              void* d_out, int out_size, void* d_ws, size_t ws_size,
                              hipStream_t stream) {
  const float* x      = (const float*)d_in[0];
  const float* rcv_w  = (const float*)d_in[1];
  const float* rcv_b  = (const float*)d_in[2];
  const float* pe_w   = (const float*)d_in[3];
  const float* pe_b   = (const float*)d_in[4];
  const float* proj_w = (const float*)d_in[5];
  const float* proj_b = (const float*)d_in[6];
  float* out = (float*)d_out;

  char* ws = (char*)d_ws;
  float* rcv = (float*)ws;                         // 28,311,552 B
  u16*   arF = (u16*)(ws + 28311552);              //  7,077,888 B
  u16*   awF = (u16*)(ws + 35389440);              //  9,437,184 B
  u16*   xTh = (u16*)(ws + 44826624);              //  4,718,592 B
  u16*   xTl = (u16*)(ws + 49545216);              //  4,718,592 B
  float* y   = (float*)(ws + 44826624);            //  9,437,184 B (aliases xTh|xTl, dead after gemm#1)
  u16*   Whr = (u16*)(ws + 54263808);              //    393,216 B
  u16*   Wlr = (u16*)(ws + 54657024);              //    393,216 B
  u16*   Whp = (u16*)(ws + 55050240);              //    131,072 B
  u16*   Wlp = (u16*)(ws + 55181312);              //    131,072 B
  // yT aliases arF/awF (free after attn_main)
  u16*   yTh = arF;
  u16*   yTl = awF;

  splitw_kernel<<<dim3(192), 256, 0, stream>>>(rcv_w, Whr, Wlr);
  splitw_kernel<<<dim3(64),  256, 0, stream>>>(proj_w, Whp, Wlp);
  split_transpose_kernel<<<dim3(36, 4, 4), 256, 0, stream>>>(x, xTh, xTl);
  gemm_mfma_kernel<<<dim3(72 * 12), 256, 0, stream>>>(Whr, Wlr, rcv_b, xTh, xTl, rcv, 768);
  row_attn_kernel<<<dim3(8, 8, 4), 256, 0, stream>>>(rcv, arF);
  col_attn_kernel<<<dim3(8, 8, 4), 256, 0, stream>>>(rcv, awF);
  attn_main_kernel<<<dim3(2048), 256, 0, stream>>>(rcv, arF, awF, pe_w, pe_b, y);
  split_transpose_kernel<<<dim3(36, 4, 4), 256, 0, stream>>>(y, yTh, yTl);
  gemm_mfma_kernel<<<dim3(72 * 4), 256, 0, stream>>>(Whp, Wlp, proj_b, yTh, yTl, out, 256);
}

// Round 10
// 153.774 us; speedup vs baseline: 1.3408x; 1.0368x over previous
//
#include <hip/hip_runtime.h>

#define S_ 2304   // 48*48

typedef unsigned short u16;
typedef __attribute__((ext_vector_type(8))) short bf16x8;
typedef __attribute__((ext_vector_type(4))) float f32x4;

static __device__ __forceinline__ u16 f2bf(float x) {
  union { float f; unsigned u; } v; v.f = x;
  unsigned r = v.u + 0x7FFFu + ((v.u >> 16) & 1u);
  return (u16)(r >> 16);
}
static __device__ __forceinline__ float bf2f(u16 h) {
  union { unsigned u; float f; } v; v.u = ((unsigned)h) << 16; return v.f;
}

// ---------------------------------------------------------------------------
// Weight split (both weight tensors in one dispatch):
// blocks 0..191 -> rcv_w (768x256), blocks 192..255 -> proj_w (256x256).
// ---------------------------------------------------------------------------
__global__ __launch_bounds__(256) void splitw_kernel(
    const float* __restrict__ w0, u16* __restrict__ wh0, u16* __restrict__ wl0,
    const float* __restrict__ w1, u16* __restrict__ wh1, u16* __restrict__ wl1)
{
  const float* w; u16 *wh, *wl; int id;
  if (blockIdx.x < 192) { w = w0; wh = wh0; wl = wl0; id = blockIdx.x * 256 + threadIdx.x; }
  else { w = w1; wh = wh1; wl = wl1; id = (blockIdx.x - 192) * 256 + threadIdx.x; }
  float4 v = ((const float4*)w)[id];
  short4 h, l;
  float f[4] = {v.x, v.y, v.z, v.w};
  u16 hh[4], ll[4];
#pragma unroll
  for (int q = 0; q < 4; q++) {
    hh[q] = f2bf(f[q]);
    ll[q] = f2bf(f[q] - bf2f(hh[q]));
  }
  h.x = hh[0]; h.y = hh[1]; h.z = hh[2]; h.w = hh[3];
  l.x = ll[0]; l.y = ll[1]; l.z = ll[2]; l.w = ll[3];
  ((short4*)wh)[id] = h;
  ((short4*)wl)[id] = l;
}

// ---------------------------------------------------------------------------
// Split-transpose: in[b][256][2304] fp32 -> outh (+outl if WRITEL)
// [b][2304][256] bf16. 64x64 tiles via LDS (u32-packed h|l). Grid (36,4,4b).
// WRITEL=false for x (2-term gemm#1 needs only Xh), true for y (proj 3-term).
// ---------------------------------------------------------------------------
template <bool WRITEL>
__global__ __launch_bounds__(256) void split_transpose_kernel(
    const float* __restrict__ in, u16* __restrict__ outh, u16* __restrict__ outl)
{
  __shared__ unsigned tile[64][65];
  const int s0 = blockIdx.x * 64, c0 = blockIdx.y * 64, b = blockIdx.z;
  const float* inb = in + (size_t)b * 256 * S_;
  u16* oh = outh + (size_t)b * S_ * 256;
  u16* ol = outl + (size_t)b * S_ * 256;
  const int tid = threadIdx.x;
#pragma unroll
  for (int it = 0; it < 4; it++) {
    int id = tid + it * 256;
    int c = id >> 4, s4 = (id & 15) * 4;
    float4 v = *(const float4*)&inb[(size_t)(c0 + c) * S_ + s0 + s4];
    float f[4] = {v.x, v.y, v.z, v.w};
#pragma unroll
    for (int q = 0; q < 4; q++) {
      u16 h = f2bf(f[q]);
      u16 l = f2bf(f[q] - bf2f(h));
      tile[s4 + q][c] = (unsigned)h | ((unsigned)l << 16);
    }
  }
  __syncthreads();
#pragma unroll
  for (int it = 0; it < 4; it++) {
    int id = tid + it * 256;
    int s = id >> 4, c4 = (id & 15) * 4;
    short4 h, l;
    unsigned p0 = tile[s][c4 + 0], p1 = tile[s][c4 + 1];
    unsigned p2 = tile[s][c4 + 2], p3 = tile[s][c4 + 3];
    h.x = (short)(p0 & 0xffff); h.y = (short)(p1 & 0xffff);
    h.z = (short)(p2 & 0xffff); h.w = (short)(p3 & 0xffff);
    *(short4*)&oh[(size_t)(s0 + s) * 256 + c0 + c4] = h;
    if (WRITEL) {
      l.x = (short)(p0 >> 16); l.y = (short)(p1 >> 16);
      l.z = (short)(p2 >> 16); l.w = (short)(p3 >> 16);
      *(short4*)&ol[(size_t)(s0 + s) * 256 + c0 + c4] = l;
    }
  }
}

// ---------------------------------------------------------------------------
// MFMA split-bf16 GEMM with B-prefetch pipeline.
// XLO=false: Out = (Wh+Wl)*Xh        (2 MFMA per mt,nt per kstep)
// XLO=true : Out = Wh*Xh+Wh*Xl+Wl*Xh (3 MFMA)
// ---------------------------------------------------------------------------
template <bool XLO>
__global__ __launch_bounds__(256) void gemm_mfma_kernel(
    const u16* __restrict__ Wh, const u16* __restrict__ Wl,
    const float* __restrict__ bias,
    const u16* __restrict__ XTh, const u16* __restrict__ XTl,
    float* __restrict__ Out, int M)
{
  __shared__ u16 wAh[2][64 * 40];   // 5120 B per buf
  __shared__ u16 wAl[2][64 * 40];
  const int MB = M >> 6;
  const int xcd = blockIdx.x & 7;
  const int idx = blockIdx.x >> 3;          // 0 .. 9*MB-1
  const int g = xcd * 9 + idx / MB;         // 0..71 group = (n_blk, b)
  const int mb = idx % MB;
  const int nb = g % 18, b = g / 18;
  const int m0 = mb * 64, n0 = nb * 128;
  const int tid = threadIdx.x;
  const int wv = tid >> 6, lane = tid & 63;
  const int lr = lane & 15, lg = lane >> 4;
  const bf16x8 zv = {0, 0, 0, 0, 0, 0, 0, 0};

  const u16* xbh = XTh + ((size_t)b * S_ + n0 + wv * 32) * 256;
  const u16* xbl = XTl + ((size_t)b * S_ + n0 + wv * 32) * 256;

  f32x4 acc[4][2];
#pragma unroll
  for (int mt = 0; mt < 4; mt++)
#pragma unroll
    for (int nt = 0; nt < 2; nt++) acc[mt][nt] = (f32x4){0.f, 0.f, 0.f, 0.f};

#define STAGE_W(t, buf)                                                      \
  {                                                                          \
    _Pragma("unroll")                                                        \
    for (int r = 0; r < 2; r++) {                                            \
      int id = tid + r * 256;                                                \
      int m = id >> 3, k4 = (id & 7) * 4;                                    \
      *(short4*)&wAh[buf][m * 40 + k4] =                                     \
          *(const short4*)&Wh[(size_t)(m0 + m) * 256 + (t) * 32 + k4];       \
      *(short4*)&wAl[buf][m * 40 + k4] =                                     \
          *(const short4*)&Wl[(size_t)(m0 + m) * 256 + (t) * 32 + k4];       \
    }                                                                        \
  }

  STAGE_W(0, 0);
  // B prologue: kstep 0
  bf16x8 cbh[2], cbl[2];
#pragma unroll
  for (int nt = 0; nt < 2; nt++) {
    size_t off = (size_t)(nt * 16 + lr) * 256 + lg * 8;
    cbh[nt] = *(const bf16x8*)&xbh[off];
    if (XLO) cbl[nt] = *(const bf16x8*)&xbl[off];
  }
  __syncthreads();

  for (int t = 0; t < 8; t++) {
    int buf = t & 1;
    if (t < 7) STAGE_W(t + 1, buf ^ 1);

    // prefetch next-kstep B fragments (global, independent of LDS bufs)
    bf16x8 nbh[2], nbl[2];
    if (t < 7) {
#pragma unroll
      for (int nt = 0; nt < 2; nt++) {
        size_t off = (size_t)(nt * 16 + lr) * 256 + (t + 1) * 32 + lg * 8;
        nbh[nt] = *(const bf16x8*)&xbh[off];
        if (XLO) nbl[nt] = *(const bf16x8*)&xbl[off];
      }
    } else {
#pragma unroll
      for (int nt = 0; nt < 2; nt++) { nbh[nt] = zv; if (XLO) nbl[nt] = zv; }
    }

    // A fragments from LDS
    bf16x8 ah[4], al[4];
#pragma unroll
    for (int mt = 0; mt < 4; mt++) {
      ah[mt] = *(const bf16x8*)&wAh[buf][(mt * 16 + lr) * 40 + lg * 8];
      al[mt] = *(const bf16x8*)&wAl[buf][(mt * 16 + lr) * 40 + lg * 8];
    }
#pragma unroll
    for (int mt = 0; mt < 4; mt++)
#pragma unroll
      for (int nt = 0; nt < 2; nt++) {
        acc[mt][nt] = __builtin_amdgcn_mfma_f32_16x16x32_bf16(ah[mt], cbh[nt], acc[mt][nt], 0, 0, 0);
        if (XLO)
          acc[mt][nt] = __builtin_amdgcn_mfma_f32_16x16x32_bf16(ah[mt], cbl[nt], acc[mt][nt], 0, 0, 0);
        acc[mt][nt] = __builtin_amdgcn_mfma_f32_16x16x32_bf16(al[mt], cbh[nt], acc[mt][nt], 0, 0, 0);
      }
    __syncthreads();
#pragma unroll
    for (int nt = 0; nt < 2; nt++) { cbh[nt] = nbh[nt]; if (XLO) cbl[nt] = nbl[nt]; }
  }

  // epilogue: D col = lane&15 (s), row = lg*4+reg (m)
  float* ob = Out + (size_t)b * M * S_;
#pragma unroll
  for (int mt = 0; mt < 4; mt++) {
    float4 b4 = *(const float4*)&bias[m0 + mt * 16 + lg * 4];
    float bv[4] = {b4.x, b4.y, b4.z, b4.w};
#pragma unroll
    for (int nt = 0; nt < 2; nt++) {
      int s = n0 + wv * 32 + nt * 16 + lr;
#pragma unroll
      for (int r = 0; r < 4; r++) {
        int m = m0 + mt * 16 + lg * 4 + r;
        ob[(size_t)m * S_ + s] = acc[mt][nt][r] + bv[r];
      }
    }
  }
#undef STAGE_W
}

// ---------------------------------------------------------------------------
// Row attention -> arF fragment-major (as r9). Softmax reduce wave-parallel:
// 4 lanes per w (192 threads), 12-iter loops + shfl_xor(1,2).
// ---------------------------------------------------------------------------
__global__ __launch_bounds__(256) void row_attn_kernel(
    const float* __restrict__ rcv, u16* __restrict__ arF)
{
  __shared__ u16  rq[16 * 2304];     // [d][i*48+w]  73728 B
  __shared__ float rk[16 * 48];
  __shared__ float Sm[48 * 49];      // [i][w] padded
  __shared__ float cmax[48], crs[48];
  const int hg = blockIdx.x, n = blockIdx.y, b = blockIdx.z;
  const float* base = rcv + ((size_t)b * 768 + n * 96) * S_;  // rq; rk at +16*S_
  const int tid = threadIdx.x;

  for (int id = tid; id < 9216; id += 256) {     // 16*2304/4 float4s
    float4 v = *(const float4*)&base[id * 4];
    short4 s;
    s.x = (short)f2bf(v.x); s.y = (short)f2bf(v.y);
    s.z = (short)f2bf(v.z); s.w = (short)f2bf(v.w);
    *(short4*)&rq[id * 4] = s;
  }

  for (int hh = 0; hh < 6; hh++) {
    int h = hg * 6 + hh;
    for (int id = tid; id < 768; id += 256) {
      int d = id / 48, w = id % 48;
      rk[id] = base[(size_t)(16 + d) * S_ + h * 48 + w];
    }
    __syncthreads();
    for (int id = tid; id < 2304; id += 256) {
      int i = id / 48, w = id % 48;
      float s = 0.f;
#pragma unroll
      for (int d = 0; d < 16; d++)
        s += bf2f(rq[d * 2304 + i * 48 + w]) * rk[d * 48 + w];
      Sm[i * 49 + w] = s * 0.25f;
    }
    __syncthreads();
    if (tid < 192) {
      int w = tid >> 2, e = tid & 3;
      float m = -1e30f;
      for (int i = e; i < 48; i += 4) m = fmaxf(m, Sm[i * 49 + w]);
      m = fmaxf(m, __shfl_xor(m, 1));
      m = fmaxf(m, __shfl_xor(m, 2));
      float s = 0.f;
      for (int i = e; i < 48; i += 4) s += __expf(Sm[i * 49 + w] - m);
      s += __shfl_xor(s, 1);
      s += __shfl_xor(s, 2);
      cmax[w] = m; crs[w] = 1.0f / s;
    }
    __syncthreads();
    u16* dst = arF + ((size_t)(b * 8 + n) * 48 + h) * 2304;
    for (int id = tid; id < 576; id += 256) {   // one 8B fragment chunk each
      int nt = id / 192, rem = id % 192, mt = rem / 64, l = rem % 64;
      int w = nt * 16 + (l & 15);
      int i0 = mt * 16 + ((l >> 4) << 2);
      short4 o;
      o.x = (short)f2bf(__expf(Sm[(i0 + 0) * 49 + w] - cmax[w]) * crs[w]);
      o.y = (short)f2bf(__expf(Sm[(i0 + 1) * 49 + w] - cmax[w]) * crs[w]);
      o.z = (short)f2bf(__expf(Sm[(i0 + 2) * 49 + w] - cmax[w]) * crs[w]);
      o.w = (short)f2bf(__expf(Sm[(i0 + 3) * 49 + w] - cmax[w]) * crs[w]);
      *(short4*)&dst[id * 4] = o;   // coalesced
    }
    __syncthreads();
  }
}

// ---------------------------------------------------------------------------
// Col attention -> awF fragment-major (as r9), wave-parallel softmax.
// ---------------------------------------------------------------------------
__global__ __launch_bounds__(256) void col_attn_kernel(
    const float* __restrict__ rcv, u16* __restrict__ awF)
{
  __shared__ float cq[16 * 48], ck[16 * 48];
  __shared__ float Tm[48 * 49];
  __shared__ float rmax[48], rrs[48];
  const int hg = blockIdx.x, n = blockIdx.y, b = blockIdx.z;
  const float* base = rcv + ((size_t)b * 768 + n * 96 + 32) * S_; // cq; ck at +16*S_
  const int tid = threadIdx.x;

  for (int hh = 0; hh < 6; hh++) {
    int h = hg * 6 + hh;
    for (int id = tid; id < 768; id += 256) {
      int d = id / 48, j = id % 48;
      cq[id] = base[(size_t)d * S_ + h * 48 + j];
      ck[id] = base[(size_t)(16 + d) * S_ + h * 48 + j];
    }
    __syncthreads();
    for (int id = tid; id < 2304; id += 256) {
      int w = id / 48, j = id % 48;
      float t = 0.f;
#pragma unroll
      for (int d = 0; d < 16; d++)
        t += ck[d * 48 + w] * cq[d * 48 + j];
      Tm[w * 49 + j] = t * 0.25f;
    }
    __syncthreads();
    if (tid < 192) {
      int w = tid >> 2, e = tid & 3;
      float m = -1e30f;
      for (int j = e; j < 48; j += 4) m = fmaxf(m, Tm[w * 49 + j]);
      m = fmaxf(m, __shfl_xor(m, 1));
      m = fmaxf(m, __shfl_xor(m, 2));
      float s = 0.f;
      for (int j = e; j < 48; j += 4) s += __expf(Tm[w * 49 + j] - m);
      s += __shfl_xor(s, 1);
      s += __shfl_xor(s, 2);
      rmax[w] = m; rrs[w] = 1.0f / s;
    }
    __syncthreads();
    u16* dst = awF + ((size_t)(b * 8 + n) * 48 + h) * 3072;
    for (int id = tid; id < 384; id += 256) {   // one 16B fragment chunk each
      int nt = id / 128, rem = id % 128, ks = rem / 64, l = rem % 64;
      int w = nt * 16 + (l & 15);
      int j0 = ks * 32 + ((l >> 4) << 3);
      u16 t8[8];
#pragma unroll
      for (int e = 0; e < 8; e++) {
        int j = j0 + e;
        t8[e] = (j < 48) ? f2bf(__expf(Tm[w * 49 + j] - rmax[w]) * rrs[w]) : (u16)0;
      }
      short4 o0, o1;
      o0.x = (short)t8[0]; o0.y = (short)t8[1]; o0.z = (short)t8[2]; o0.w = (short)t8[3];
      o1.x = (short)t8[4]; o1.y = (short)t8[5]; o1.z = (short)t8[6]; o1.w = (short)t8[7];
      *(short4*)&dst[id * 8]     = o0;
      *(short4*)&dst[id * 8 + 4] = o1;
    }
    __syncthreads();
  }
}

// ---------------------------------------------------------------------------
// Main contraction + PE conv (unchanged from r9: 2048 blocks, 2 v-planes,
// fragment-major coalesced aw/ar loads).
// ---------------------------------------------------------------------------
__global__ __launch_bounds__(256) void attn_main_kernel(
    const float* __restrict__ rcv, const u16* __restrict__ arF,
    const u16* __restrict__ awF, const float* __restrict__ pe_w,
    const float* __restrict__ pe_b, float* __restrict__ y)
{
  __shared__ u16 vA[96 * 72];         // 13824 B  [(dloc,i)][j pad]
  const int id0 = blockIdx.x;
  const int n = id0 & 7;              // XCD swizzle
  const int rest = id0 >> 3;          // 0..255
  const int b = rest >> 6;            // 0..3
  const int inner = rest & 63;        // 0..63
  const int dchunk = inner >> 2;      // 0..15 (2 planes each)
  const int hc = inner & 3;           // 0..3
  const int tid = threadIdx.x;
  const int wave = tid >> 6, lane = tid & 63;
  const int dl = wave >> 1, half = wave & 1;
  const int h0 = hc * 12 + half * 6;
  const int lr = lane & 15, lg = lane >> 4;

  // zero only the j-pad columns (48..71); staging fills cols 0..47
  for (int id = tid; id < 96 * 24; id += 256) {
    int row = id / 24, col = 48 + id % 24;
    vA[row * 72 + col] = 0;
  }
  const float* vbase = rcv + ((size_t)b * 768 + n * 96 + 64 + dchunk * 2) * S_;
  for (int id = tid; id < 1152; id += 256) {   // 2 planes * 576 float4
    int dl2 = id / 576, rem = id % 576;
    int i = rem / 12, j4 = (rem % 12) * 4;
    float4 v = *(const float4*)&vbase[(size_t)dl2 * S_ + i * 48 + j4];
    short4 s;
    s.x = (short)f2bf(v.x); s.y = (short)f2bf(v.y);
    s.z = (short)f2bf(v.z); s.w = (short)f2bf(v.w);
    *(short4*)&vA[(dl2 * 48 + i) * 72 + j4] = s;
  }
  __syncthreads();   // the only barrier

  const size_t bn48 = (size_t)(b * 8 + n) * 48;
  const int c = n * 32 + dchunk * 2 + dl;   // global channel of this wave's d-plane
  float pw[9];
#pragma unroll
  for (int t = 0; t < 9; t++) pw[t] = pe_w[c * 9 + t];
  const float pb = pe_b[c];
  float* yg = y + ((size_t)b * 256 + c) * S_;
  const int vrow0 = dl * 48;

  for (int hh = 0; hh < 6; hh++) {
    int h = h0 + hh;
    const u16* awg = awF + (bn48 + h) * 3072;  // fragment-major
    const u16* arg = arF + (bn48 + h) * 2304;  // fragment-major

    // B fragments: lane-consecutive 16B loads (coalesced)
    bf16x8 bf0[3], bf1[3];
#pragma unroll
    for (int nt = 0; nt < 3; nt++) {
      bf0[nt] = *(const bf16x8*)&awg[nt * 1024 + lane * 8];        // ks=0: j 0..31
      bf1[nt] = *(const bf16x8*)&awg[nt * 1024 + 512 + lane * 8];  // ks=1: j 32..47|0
    }

    f32x4 acc[3][3];
#pragma unroll
    for (int mt = 0; mt < 3; mt++)
#pragma unroll
      for (int nt = 0; nt < 3; nt++) acc[mt][nt] = (f32x4){0.f, 0.f, 0.f, 0.f};

#pragma unroll
    for (int mt = 0; mt < 3; mt++) {
      bf16x8 a0 = *(const bf16x8*)&vA[(vrow0 + mt * 16 + lr) * 72 + lg * 8];
      bf16x8 a1 = *(const bf16x8*)&vA[(vrow0 + mt * 16 + lr) * 72 + 32 + lg * 8];
#pragma unroll
      for (int nt = 0; nt < 3; nt++) {
        acc[mt][nt] = __builtin_amdgcn_mfma_f32_16x16x32_bf16(a0, bf0[nt], acc[mt][nt], 0, 0, 0);
        acc[mt][nt] = __builtin_amdgcn_mfma_f32_16x16x32_bf16(a1, bf1[nt], acc[mt][nt], 0, 0, 0);
      }
    }

    // contract i with ar (lane-consecutive 8B loads), reduce over lane groups
    float pv[3];
#pragma unroll
    for (int nt = 0; nt < 3; nt++) {
      float p = 0.f;
#pragma unroll
      for (int mt = 0; mt < 3; mt++) {
        short4 s = *(const short4*)&arg[(nt * 3 + mt) * 256 + lane * 4];
        p += bf2f((u16)s.x) * acc[mt][nt][0] + bf2f((u16)s.y) * acc[mt][nt][1]
           + bf2f((u16)s.z) * acc[mt][nt][2] + bf2f((u16)s.w) * acc[mt][nt][3];
      }
      p += __shfl_xor(p, 16);
      p += __shfl_xor(p, 32);
      pv[nt] = p;             // all lanes: value for w = nt*16 + lr
    }

    // lanes 0..47 write w=lane: PE depthwise 3x3 from resident v + store
    if (lane < 48) {
      float a = (lane < 16) ? pv[0] : (lane < 32 ? pv[1] : pv[2]);
      a += pb;
      int ww = lane;
#pragma unroll
      for (int kh = -1; kh <= 1; kh++) {
        int ih = h + kh;
        if (ih < 0 || ih > 47) continue;
#pragma unroll
        for (int kw = -1; kw <= 1; kw++) {
          int jw = ww + kw;
          if (jw < 0 || jw > 47) continue;
          a += pw[(kh + 1) * 3 + (kw + 1)] * bf2f(vA[(vrow0 + ih) * 72 + jw]);
        }
      }
      yg[h * 48 + ww] = a;
    }
  }
}

// ---------------------------------------------------------------------------
extern "C" void kernel_launch(void* const* d_in, const int* in_sizes, int n_in,
                              void* d_out, int out_size, void* d_ws, size_t ws_size,
                              hipStream_t stream) {
  const float* x      = (const float*)d_in[0];
  const float* rcv_w  = (const float*)d_in[1];
  const float* rcv_b  = (const float*)d_in[2];
  const float* pe_w   = (const float*)d_in[3];
  const float* pe_b   = (const float*)d_in[4];
  const float* proj_w = (const float*)d_in[5];
  const float* proj_b = (const float*)d_in[6];
  float* out = (float*)d_out;

  char* ws = (char*)d_ws;
  float* rcv = (float*)ws;                         // 28,311,552 B
  u16*   arF = (u16*)(ws + 28311552);              //  7,077,888 B
  u16*   awF = (u16*)(ws + 35389440);              //  9,437,184 B
  u16*   xTh = (u16*)(ws + 44826624);              //  4,718,592 B
  float* y   = (float*)(ws + 49545216);            //  9,437,184 B
  u16*   Whr = (u16*)(ws + 58982400);              //    393,216 B
  u16*   Wlr = (u16*)(ws + 59375616);              //    393,216 B
  u16*   Whp = (u16*)(ws + 59768832);              //    131,072 B
  u16*   Wlp = (u16*)(ws + 59899904);              //    131,072 B
  // yT aliases arF/awF (free after attn_main)
  u16*   yTh = arF;
  u16*   yTl = awF;

  splitw_kernel<<<dim3(256), 256, 0, stream>>>(rcv_w, Whr, Wlr, proj_w, Whp, Wlp);
  split_transpose_kernel<false><<<dim3(36, 4, 4), 256, 0, stream>>>(x, xTh, xTh);
  gemm_mfma_kernel<false><<<dim3(72 * 12), 256, 0, stream>>>(Whr, Wlr, rcv_b, xTh, xTh, rcv, 768);
  row_attn_kernel<<<dim3(8, 8, 4), 256, 0, stream>>>(rcv, arF);
  col_attn_kernel<<<dim3(8, 8, 4), 256, 0, stream>>>(rcv, awF);
  attn_main_kernel<<<dim3(2048), 256, 0, stream>>>(rcv, arF, awF, pe_w, pe_b, y);
  split_transpose_kernel<true><<<dim3(36, 4, 4), 256, 0, stream>>>(y, yTh, yTl);
  gemm_mfma_kernel<true><<<dim3(72 * 4), 256, 0, stream>>>(Whp, Wlp, proj_b, yTh, yTl, out, 256);
}